// Round 6
// baseline (3027.311 us; speedup 1.0000x reference)
//
#include <hip/hip_runtime.h>

#define NN 50000
#define NE 600000
#define DD 128
#define LL 3
#define GG 512
#define NB_SCAN 98   // ceil(NN/512)

// ---- marker for host-side input-layout mismatch (f32 out) ----
__global__ void k_mark(float* __restrict__ out, float val, int n){
    int i = blockIdx.x*256 + threadIdx.x; if (i >= n) return;
    out[i] = (i == 0) ? val : 0.f;
}

// ---------------- embed: x[i,c] = tab[clip(d[i],0,5), c] ----------------
__global__ void k_embed(const int* __restrict__ d, const float* __restrict__ tab,
                        float* __restrict__ x){
    int idx = blockIdx.x*256 + threadIdx.x;
    if (idx >= NN*DD) return;
    int row = idx >> 7, c = idx & 127;
    int di = d[row]; di = di < 0 ? 0 : (di > 5 ? 5 : di);
    x[idx] = tab[di*DD + c];
}

// ---------------- group offsets: goff[g] = lower_bound(batch_ids, g) ----------------
__global__ void k_goff(const int* __restrict__ bids, int* __restrict__ goff){
    int g = blockIdx.x*256 + threadIdx.x;
    if (g > GG) return;
    int lo = 0, hi = NN;
    while (lo < hi){ int mid = (lo+hi) >> 1; if (bids[mid] < g) lo = mid+1; else hi = mid; }
    goff[g] = lo;
}

// ---------------- CSR build ----------------
__global__ void k_count(const int* __restrict__ dst, int* __restrict__ cnt){
    int e = blockIdx.x*256 + threadIdx.x; if (e >= NE) return;
    atomicAdd(&cnt[dst[e]], 1);
}
__global__ void k_scanA(const int* __restrict__ cnt, int* __restrict__ inc, int* __restrict__ bsum){
    __shared__ int s[512];
    int i = blockIdx.x*512 + threadIdx.x;
    int v = (i < NN) ? cnt[i] : 0;
    s[threadIdx.x] = v; __syncthreads();
    for (int off = 1; off < 512; off <<= 1){
        int add = (threadIdx.x >= off) ? s[threadIdx.x - off] : 0;
        __syncthreads();
        s[threadIdx.x] += add;
        __syncthreads();
    }
    if (i < NN) inc[i] = s[threadIdx.x];
    if (threadIdx.x == 511) bsum[blockIdx.x] = s[511];
}
__global__ void k_scanB(const int* __restrict__ bsum, int* __restrict__ boff){
    if (threadIdx.x == 0 && blockIdx.x == 0){
        int acc = 0;
        for (int b = 0; b < NB_SCAN; b++){ boff[b] = acc; acc += bsum[b]; }
        boff[NB_SCAN] = acc;
    }
}
__global__ void k_scanC(const int* __restrict__ cnt, const int* __restrict__ inc,
                        const int* __restrict__ boff, int* __restrict__ rowptr,
                        int* __restrict__ cursor){
    int i = blockIdx.x*512 + threadIdx.x;
    if (i < NN){
        int e = boff[blockIdx.x] + inc[i] - cnt[i];
        rowptr[i] = e; cursor[i] = e;
    } else if (i == NN){
        rowptr[NN] = NE;
    }
}
__global__ void k_fill(const int* __restrict__ src, const int* __restrict__ dst,
                       int* __restrict__ cursor, int* __restrict__ eidx){
    int e = blockIdx.x*256 + threadIdx.x; if (e >= NE) return;
    int p = atomicAdd(&cursor[dst[e]], 1);
    eidx[p] = src[e];
}

// ---- aggregation IN-PLACE: x[v,:] = x[v,:]*(1+eps_l) + sum_{e: dst=v} y[src_e,:] ----
__global__ void k_agg(float* __restrict__ x, const float* __restrict__ y,
                      const int* __restrict__ rowptr, const int* __restrict__ eidx,
                      const float* __restrict__ epsP, int l){
    int node = blockIdx.x*8 + (threadIdx.x >> 5);
    if (node >= NN) return;
    int c4 = (threadIdx.x & 31) << 2;
    float epl = 1.0f + epsP[l];
    float4 acc = *(const float4*)(x + (size_t)node*DD + c4);
    acc.x *= epl; acc.y *= epl; acc.z *= epl; acc.w *= epl;
    int e0 = rowptr[node], e1 = rowptr[node+1];
    for (int e = e0; e < e1; e++){
        int s = eidx[e];
        float4 v = *(const float4*)(y + (size_t)s*DD + c4);
        acc.x += v.x; acc.y += v.y; acc.z += v.z; acc.w += v.w;
    }
    *(float4*)(x + (size_t)node*DD + c4) = acc;
}

// ---------------- naive GEMMs: one thread per output element ----------------
__global__ void k_lin(const float* __restrict__ A, const float* __restrict__ W,
                      const float* __restrict__ bias, float* __restrict__ C){
    int idx = blockIdx.x*256 + threadIdx.x;
    if (idx >= NN*DD) return;
    int row = idx >> 7, col = idx & 127;
    float acc = bias[col];
    const float* a = A + (size_t)row*DD;
    for (int k = 0; k < DD; k++) acc = fmaf(a[k], W[k*DD + col], acc);
    C[idx] = fmaxf(acc, 0.f);
}
__global__ void k_mm(const float* __restrict__ A, const float* __restrict__ W,
                     float* __restrict__ C){
    int idx = blockIdx.x*256 + threadIdx.x;
    if (idx >= NN*DD) return;
    int row = idx >> 7, col = idx & 127;
    float acc = 0.f;
    const float* a = A + (size_t)row*DD;
    for (int k = 0; k < DD; k++) acc = fmaf(a[k], W[k*DD + col], acc);
    C[idx] = acc;
}
__global__ void k_mmbn(const float* __restrict__ A, const float* __restrict__ W,
                       const float* __restrict__ ss, float* __restrict__ C){
    int idx = blockIdx.x*256 + threadIdx.x;
    if (idx >= NN*DD) return;
    int row = idx >> 7, col = idx & 127;
    float acc = 0.f;
    const float* a = A + (size_t)row*DD;
    for (int k = 0; k < DD; k++){
        float v = fmaxf(fmaf(a[k], ss[k], ss[DD + k]), 0.f);
        acc = fmaf(v, W[k*DD + col], acc);
    }
    C[idx] = acc;
}

// ---------------- BN stats: one block per column ----------------
__global__ void k_bncol(const float* __restrict__ A, float* __restrict__ stats){
    int c = blockIdx.x;            // 128 blocks
    int t = threadIdx.x;           // 256 threads
    float s = 0.f, q = 0.f;
    for (int r = t; r < NN; r += 256){
        float v = A[(size_t)r*DD + c];
        s += v; q += v*v;
    }
    __shared__ float ls[256], lq[256];
    ls[t] = s; lq[t] = q; __syncthreads();
    for (int off = 128; off > 0; off >>= 1){
        if (t < off){ ls[t] += ls[t+off]; lq[t] += lq[t+off]; }
        __syncthreads();
    }
    if (t == 0){ stats[c] = ls[0]; stats[c + DD] = lq[0]; }
}
__global__ void k_bnfin(const float* __restrict__ stats, const float* __restrict__ g,
                        const float* __restrict__ b, float* __restrict__ ss){
    int c = threadIdx.x; if (c >= DD) return;
    float mu  = stats[c] * (1.0f/NN);
    float var = stats[c + DD] * (1.0f/NN) - mu*mu;
    float sc  = rsqrtf(fmaxf(var, 0.f) + 1e-5f) * g[c];
    ss[c] = sc;
    ss[c + DD] = b[c] - mu*sc;
}
__global__ void k_bnrelu(float* __restrict__ x, const float* __restrict__ ss){
    int idx = blockIdx.x*256 + threadIdx.x;
    if (idx >= NN*DD) return;
    int c = idx & 127;
    x[idx] = fmaxf(fmaf(x[idx], ss[c], ss[DD + c]), 0.f);
}

// ---------------- pooling: per-graph mean over sorted row range (f32 out) ----------------
__global__ void k_pool(const float* __restrict__ x, const int* __restrict__ goff,
                       float* __restrict__ outp, float* __restrict__ outf){
    int g = blockIdx.x;
    int c = threadIdx.x;           // 128 threads
    int r0 = goff[g], r1 = goff[g+1];
    float acc = 0.f;
    for (int r = r0; r < r1; r++) acc += x[(size_t)r*DD + c];
    float m = acc / fmaxf((float)(r1 - r0), 1.0f);
    outp[g*DD + c] = m;
    if (outf) outf[g*DD + c] = m;
}

// ---------------- predict head (f32 out) ----------------
__global__ void k_pred1(const float* __restrict__ hg, const float* __restrict__ W1,
                        const float* __restrict__ b1, float* __restrict__ ph){
    int idx = blockIdx.x*256 + threadIdx.x;
    if (idx >= GG*256) return;
    int g = idx >> 8, j = idx & 255;
    float acc = b1[j];
    for (int k = 0; k < DD; k++) acc = fmaf(hg[g*DD + k], W1[k*256 + j], acc);
    ph[idx] = fmaxf(acc, 0.f);
}
__global__ void k_pred2(const float* __restrict__ ph, const float* __restrict__ W2,
                        const float* __restrict__ b2, float* __restrict__ out){
    int g = blockIdx.x*256 + threadIdx.x; if (g >= GG) return;
    float acc = b2[0];
    for (int k = 0; k < 256; k++) acc = fmaf(ph[g*256 + k], W2[k], acc);
    out[g] = acc;
}

extern "C" void kernel_launch(void* const* d_in, const int* in_sizes, int n_in,
                              void* d_out, int out_size, void* d_ws, size_t ws_size,
                              hipStream_t stream){
    float* out = (float*)d_out;                   // reference outputs are float32
    const int OUT_N = GG + GG*DD + LL*GG*DD;      // 262656

    // ---- host-side input-layout guard ----
    static const int EXP[24] = {50000,600000,600000,50000, 768,49152,384,49152,384,384,
                                49152,3,384,384,16384,128,128,16384,128,128,
                                32768,256,256,1};
    int bad = -1;
    if (n_in != 24) bad = 50;
    else for (int i = 0; i < 24; i++) if (in_sizes[i] != EXP[i]) { bad = i; break; }
    if (bad >= 0){
        k_mark<<<(OUT_N+255)/256, 256, 0, stream>>>(out, 2048.0f + (float)bad, OUT_N);
        return;
    }

    const int* d    = (const int*)d_in[0];
    const int* src  = (const int*)d_in[1];
    const int* dst  = (const int*)d_in[2];
    const int* bids = (const int*)d_in[3];
    const float* emb  = (const float*)d_in[4];
    const float* linW = (const float*)d_in[5];
    const float* linB = (const float*)d_in[6];
    const float* W1   = (const float*)d_in[7];
    const float* g1   = (const float*)d_in[8];
    const float* b1   = (const float*)d_in[9];
    const float* W2   = (const float*)d_in[10];
    const float* epsA = (const float*)d_in[11];
    const float* bng  = (const float*)d_in[12];
    const float* bnb  = (const float*)d_in[13];
    const float* pW1  = (const float*)d_in[14];
    const float* pg1  = (const float*)d_in[15];
    const float* pb1  = (const float*)d_in[16];
    const float* pW2  = (const float*)d_in[17];
    const float* pbng = (const float*)d_in[18];
    const float* pbnb = (const float*)d_in[19];
    const float* prW1 = (const float*)d_in[20];
    const float* prb1 = (const float*)d_in[21];
    const float* prW2 = (const float*)d_in[22];
    const float* prb2 = (const float*)d_in[23];

    // ---- workspace (~54 MB) ----
    float* x     = (float*)d_ws;                  // NN*DD
    float* y     = x + (size_t)NN*DD;             // NN*DD
    float* stats = y + (size_t)NN*DD;             // 256
    float* ss    = stats + 2*DD;                  // 256
    float* hg    = ss + 2*DD;                     // GG*DD
    float* ph    = hg + (size_t)GG*DD;            // GG*256
    int* cnt    = (int*)(ph + (size_t)GG*256);
    int* inc    = cnt + NN;
    int* rowptr = inc + NN;                       // N+1
    int* cursor = rowptr + NN + 1;
    int* eidx   = cursor + NN;                    // E
    int* goff   = eidx + NE;                      // G+1
    int* bsum   = goff + GG + 1;                  // NB_SCAN
    int* boff   = bsum + NB_SCAN;                 // NB_SCAN+1

    float* out_pred   = out;                      // [G]
    float* out_hgraph = out + GG;                 // [G,D]
    float* out_hmeans = out + GG + GG*DD;         // [L,G,D]

    const int NW_GRID  = (NN*DD + 255)/256;       // 25000
    const int E_GRID   = (NE + 255)/256;          // 2344
    const int AGG_GRID = (NN + 7)/8;              // 6250

    // node features
    k_embed<<<NW_GRID, 256, 0, stream>>>(d, emb, x);
    // graph boundaries
    k_goff<<<3, 256, 0, stream>>>(bids, goff);
    // CSR by dst (graph fixed across layers -> build once)
    hipMemsetAsync(cnt, 0, NN*sizeof(int), stream);
    k_count<<<E_GRID, 256, 0, stream>>>(dst, cnt);
    k_scanA<<<NB_SCAN, 512, 0, stream>>>(cnt, inc, bsum);
    k_scanB<<<1, 64, 0, stream>>>(bsum, boff);
    k_scanC<<<NB_SCAN, 512, 0, stream>>>(cnt, inc, boff, rowptr, cursor);
    k_fill<<<E_GRID, 256, 0, stream>>>(src, dst, cursor, eidx);

    for (int l = 0; l < LL; l++){
        // y = relu(x @ lin_W + lin_b)
        k_lin<<<NW_GRID, 256, 0, stream>>>(x, linW + (size_t)l*DD*DD, linB + (size_t)l*DD, y);
        // x = x*(1+eps) + gather-sum(y)   (in-place)
        k_agg<<<AGG_GRID, 256, 0, stream>>>(x, y, rowptr, eidx, epsA, l);
        // y = x @ mlp_W1
        k_mm<<<NW_GRID, 256, 0, stream>>>(x, W1 + (size_t)l*DD*DD, y);
        k_bncol<<<DD, 256, 0, stream>>>(y, stats);
        k_bnfin<<<1, 128, 0, stream>>>(stats, g1 + (size_t)l*DD, b1 + (size_t)l*DD, ss);
        // x = relu(bn(y)) @ mlp_W2
        k_mmbn<<<NW_GRID, 256, 0, stream>>>(y, W2 + (size_t)l*DD*DD, ss, x);
        k_bncol<<<DD, 256, 0, stream>>>(x, stats);
        k_bnfin<<<1, 128, 0, stream>>>(stats, bng + (size_t)l*DD, bnb + (size_t)l*DD, ss);
        k_bnrelu<<<NW_GRID, 256, 0, stream>>>(x, ss);
        // h_means[l]
        k_pool<<<GG, 128, 0, stream>>>(x, goff, out_hmeans + (size_t)l*GG*DD, nullptr);
    }

    // pooling MLP: p = relu(bn(x @ pool_W1)) @ pool_W2 ; p = relu(bn(p))
    k_mm<<<NW_GRID, 256, 0, stream>>>(x, pW1, y);
    k_bncol<<<DD, 256, 0, stream>>>(y, stats);
    k_bnfin<<<1, 128, 0, stream>>>(stats, pg1, pb1, ss);
    k_mmbn<<<NW_GRID, 256, 0, stream>>>(y, pW2, ss, x);
    k_bncol<<<DD, 256, 0, stream>>>(x, stats);
    k_bnfin<<<1, 128, 0, stream>>>(stats, pbng, pbnb, ss);
    k_bnrelu<<<NW_GRID, 256, 0, stream>>>(x, ss);       // p in x
    // h_graph (f32 out + copy for predict head)
    k_pool<<<GG, 128, 0, stream>>>(x, goff, out_hgraph, hg);
    // predict
    k_pred1<<<GG, 256, 0, stream>>>(hg, prW1, prb1, ph);
    k_pred2<<<2, 256, 0, stream>>>(ph, prW2, prb2, out_pred);
}

// Round 7
// 882.410 us; speedup vs baseline: 3.4307x; 3.4307x over previous
//
#include <hip/hip_runtime.h>

#define NN 50000
#define NE 600000
#define DD 128
#define LL 3
#define GG 512
#define NB_SCAN 98   // ceil(NN/512)

// ---- marker for host-side input-layout mismatch (f32 out) ----
__global__ void k_mark(float* __restrict__ out, float val, int n){
    int i = blockIdx.x*256 + threadIdx.x; if (i >= n) return;
    out[i] = (i == 0) ? val : 0.f;
}

// ---------------- embed ----------------
__global__ void k_embed(const int* __restrict__ d, const float* __restrict__ tab,
                        float* __restrict__ x){
    int idx = blockIdx.x*256 + threadIdx.x;
    if (idx >= NN*DD) return;
    int row = idx >> 7, c = idx & 127;
    int di = d[row]; di = di < 0 ? 0 : (di > 5 ? 5 : di);
    x[idx] = tab[di*DD + c];
}

// ---------------- group offsets ----------------
__global__ void k_goff(const int* __restrict__ bids, int* __restrict__ goff){
    int g = blockIdx.x*256 + threadIdx.x;
    if (g > GG) return;
    int lo = 0, hi = NN;
    while (lo < hi){ int mid = (lo+hi) >> 1; if (bids[mid] < g) lo = mid+1; else hi = mid; }
    goff[g] = lo;
}

// ---------------- CSR build ----------------
__global__ void k_count(const int* __restrict__ dst, int* __restrict__ cnt){
    int e = blockIdx.x*256 + threadIdx.x; if (e >= NE) return;
    atomicAdd(&cnt[dst[e]], 1);
}
__global__ void k_scanA(const int* __restrict__ cnt, int* __restrict__ inc, int* __restrict__ bsum){
    __shared__ int s[512];
    int i = blockIdx.x*512 + threadIdx.x;
    int v = (i < NN) ? cnt[i] : 0;
    s[threadIdx.x] = v; __syncthreads();
    for (int off = 1; off < 512; off <<= 1){
        int add = (threadIdx.x >= off) ? s[threadIdx.x - off] : 0;
        __syncthreads();
        s[threadIdx.x] += add;
        __syncthreads();
    }
    if (i < NN) inc[i] = s[threadIdx.x];
    if (threadIdx.x == 511) bsum[blockIdx.x] = s[511];
}
__global__ void k_scanB(const int* __restrict__ bsum, int* __restrict__ boff){
    if (threadIdx.x == 0 && blockIdx.x == 0){
        int acc = 0;
        for (int b = 0; b < NB_SCAN; b++){ boff[b] = acc; acc += bsum[b]; }
        boff[NB_SCAN] = acc;
    }
}
__global__ void k_scanC(const int* __restrict__ cnt, const int* __restrict__ inc,
                        const int* __restrict__ boff, int* __restrict__ rowptr,
                        int* __restrict__ cursor){
    int i = blockIdx.x*512 + threadIdx.x;
    if (i < NN){
        int e = boff[blockIdx.x] + inc[i] - cnt[i];
        rowptr[i] = e; cursor[i] = e;
    } else if (i == NN){
        rowptr[NN] = NE;
    }
}
__global__ void k_fill(const int* __restrict__ src, const int* __restrict__ dst,
                       int* __restrict__ cursor, int* __restrict__ eidx){
    int e = blockIdx.x*256 + threadIdx.x; if (e >= NE) return;
    int p = atomicAdd(&cursor[dst[e]], 1);
    eidx[p] = src[e];
}

// ---- aggregation IN-PLACE, optional BN+ReLU on the self-term ----
// x[v,:] = f(x[v,:])*(1+eps_l) + sum_{e: dst=v} y[src_e,:], f = relu(bn) if ss else id
__global__ void k_agg(float* __restrict__ x, const float* __restrict__ y,
                      const int* __restrict__ rowptr, const int* __restrict__ eidx,
                      const float* __restrict__ epsP, int l, const float* __restrict__ ss){
    int node = blockIdx.x*8 + (threadIdx.x >> 5);
    if (node >= NN) return;
    int c4 = (threadIdx.x & 31) << 2;
    float epl = 1.0f + epsP[l];
    float4 acc = *(const float4*)(x + (size_t)node*DD + c4);
    if (ss){
        acc.x = fmaxf(fmaf(acc.x, ss[c4+0], ss[DD+c4+0]), 0.f);
        acc.y = fmaxf(fmaf(acc.y, ss[c4+1], ss[DD+c4+1]), 0.f);
        acc.z = fmaxf(fmaf(acc.z, ss[c4+2], ss[DD+c4+2]), 0.f);
        acc.w = fmaxf(fmaf(acc.w, ss[c4+3], ss[DD+c4+3]), 0.f);
    }
    acc.x *= epl; acc.y *= epl; acc.z *= epl; acc.w *= epl;
    int e0 = rowptr[node], e1 = rowptr[node+1];
    for (int e = e0; e < e1; e++){
        int s = eidx[e];
        float4 v = *(const float4*)(y + (size_t)s*DD + c4);
        acc.x += v.x; acc.y += v.y; acc.z += v.z; acc.w += v.w;
    }
    *(float4*)(x + (size_t)node*DD + c4) = acc;
}

// ---------------- bn finalize: stats(sum,sumsq) -> scale/shift ----------------
__global__ void k_bnfin(const float* __restrict__ stats, const float* __restrict__ g,
                        const float* __restrict__ b, float* __restrict__ ss){
    int c = threadIdx.x; if (c >= DD) return;
    float mu  = stats[c] * (1.0f/NN);
    float var = stats[c + DD] * (1.0f/NN) - mu*mu;
    float sc  = rsqrtf(fmaxf(var, 0.f) + 1e-5f) * g[c];
    ss[c] = sc;
    ss[c + DD] = b[c] - mu*sc;
}

// ---------------- tiled GEMM: C[M,128] = op(A') @ W, optional fused BN-stats of C ----
// AMODE: 0 plain A; 2 A'=relu(A*sc+sh) during staging
// OMODE: 0 plain store; 1 relu(C + bias)
// STATS: 1 -> atomicAdd per-column sum/sumsq of C into stats[256] (rows<M only)
template<int AMODE, int OMODE, int STATS>
__global__ __launch_bounds__(128) void k_gemm(
    const float* __restrict__ A, const float* __restrict__ W,
    const float* __restrict__ bias, const float* __restrict__ ss,
    float* __restrict__ C, float* __restrict__ stats, int M)
{
    __shared__ float Al[64*36];
    __shared__ float Wl[32*132];
    const int t = threadIdx.x;
    const int ty = t >> 4, tx = t & 15;          // ty 0..7, tx 0..15
    const int rowBase = blockIdx.x * 64;
    const int c0 = tx*4, c1 = 64 + tx*4;         // 2-way-bank-free column split

    float acc[8][8];
#pragma unroll
    for (int r = 0; r < 8; r++)
#pragma unroll
        for (int c = 0; c < 8; c++) acc[r][c] = 0.f;

#pragma unroll 1
    for (int kc = 0; kc < DD; kc += 32){
        // stage A tile (64 x 32), optional fused BN+ReLU
#pragma unroll
        for (int q = 0; q < 4; q++){
            int id = q*128 + t;
            int r  = id >> 3;
            int kq = (id & 7) << 2;
            int gr = rowBase + r;
            float4 av = make_float4(0.f, 0.f, 0.f, 0.f);
            if (gr < M) av = *(const float4*)(A + (size_t)gr*DD + kc + kq);
            if (AMODE == 2){
                int cc = kc + kq;
                av.x = fmaxf(fmaf(av.x, ss[cc+0], ss[DD+cc+0]), 0.f);
                av.y = fmaxf(fmaf(av.y, ss[cc+1], ss[DD+cc+1]), 0.f);
                av.z = fmaxf(fmaf(av.z, ss[cc+2], ss[DD+cc+2]), 0.f);
                av.w = fmaxf(fmaf(av.w, ss[cc+3], ss[DD+cc+3]), 0.f);
            }
            *(float4*)(Al + r*36 + kq) = av;
        }
        // stage W tile (32 x 128)
#pragma unroll
        for (int q = 0; q < 4; q++){
            int id = q*128 + t;
            int rr = id >> 4;
            int c8 = (id & 15) << 3;
            float4 lo = *(const float4*)(W + (size_t)(kc+rr)*DD + c8);
            float4 hi = *(const float4*)(W + (size_t)(kc+rr)*DD + c8 + 4);
            *(float4*)(Wl + rr*132 + c8)     = lo;
            *(float4*)(Wl + rr*132 + c8 + 4) = hi;
        }
        __syncthreads();
#pragma unroll 1
        for (int k = 0; k < 32; k += 4){
            float as[8][4];
#pragma unroll
            for (int r = 0; r < 8; r++){
                float4 a4 = *(const float4*)(Al + (ty + r*8)*36 + k);
                as[r][0] = a4.x; as[r][1] = a4.y; as[r][2] = a4.z; as[r][3] = a4.w;
            }
#pragma unroll
            for (int kk = 0; kk < 4; kk++){
                float4 wlo = *(const float4*)(Wl + (k+kk)*132 + c0);
                float4 whi = *(const float4*)(Wl + (k+kk)*132 + c1);
                float w[8] = {wlo.x, wlo.y, wlo.z, wlo.w, whi.x, whi.y, whi.z, whi.w};
#pragma unroll
                for (int r = 0; r < 8; r++){
                    float a = as[r][kk];
#pragma unroll
                    for (int c = 0; c < 8; c++) acc[r][c] = fmaf(a, w[c], acc[r][c]);
                }
            }
        }
        __syncthreads();
    }

    // epilogue: store + optional bias/relu
#pragma unroll
    for (int r = 0; r < 8; r++){
        int gr = rowBase + ty + r*8;
        if (gr >= M) continue;
        float o[8];
#pragma unroll
        for (int c = 0; c < 8; c++) o[c] = acc[r][c];
        if (OMODE == 1){
#pragma unroll
            for (int c = 0; c < 4; c++){
                o[c]   = fmaxf(o[c]   + bias[c0 + c], 0.f);
                o[c+4] = fmaxf(o[c+4] + bias[c1 + c], 0.f);
            }
        }
        *(float4*)(C + (size_t)gr*DD + c0) = make_float4(o[0], o[1], o[2], o[3]);
        *(float4*)(C + (size_t)gr*DD + c1) = make_float4(o[4], o[5], o[6], o[7]);
    }

    if (STATS){
        // per-thread col partials over its 8 rows (skip pad rows)
        float cs[8], cq[8];
#pragma unroll
        for (int c = 0; c < 8; c++){ cs[c] = 0.f; cq[c] = 0.f; }
#pragma unroll
        for (int r = 0; r < 8; r++){
            if (rowBase + ty + r*8 >= M) continue;
#pragma unroll
            for (int c = 0; c < 8; c++){
                float v = acc[r][c];
                cs[c] += v; cq[c] += v*v;
            }
        }
        // LDS reduce across ty (reuse Al for sums, Wl for sumsq)
#pragma unroll
        for (int c = 0; c < 4; c++){
            Al[ty*128 + c0 + c] = cs[c];   Al[ty*128 + c1 + c] = cs[c+4];
            Wl[ty*128 + c0 + c] = cq[c];   Wl[ty*128 + c1 + c] = cq[c+4];
        }
        __syncthreads();
        if (t < 128){
            float s = 0.f, q = 0.f;
#pragma unroll
            for (int u = 0; u < 8; u++){ s += Al[u*128 + t]; q += Wl[u*128 + t]; }
            atomicAdd(&stats[t], s);
            atomicAdd(&stats[t + DD], q);
        }
    }
}

// ---------------- pooling with fused BN+ReLU: mean_g relu(bn(h)) ----------------
__global__ void k_poolbn(const float* __restrict__ h, const float* __restrict__ ss,
                         const int* __restrict__ goff, float* __restrict__ outp,
                         float* __restrict__ outf){
    int g = blockIdx.x;
    int c = threadIdx.x;           // 128 threads
    float sc = ss[c], sh = ss[DD + c];
    int r0 = goff[g], r1 = goff[g+1];
    float acc = 0.f;
    for (int r = r0; r < r1; r++)
        acc += fmaxf(fmaf(h[(size_t)r*DD + c], sc, sh), 0.f);
    float m = acc / fmaxf((float)(r1 - r0), 1.0f);
    outp[g*DD + c] = m;
    if (outf) outf[g*DD + c] = m;
}

// ---------------- predict head ----------------
__global__ void k_pred1(const float* __restrict__ hg, const float* __restrict__ W1,
                        const float* __restrict__ b1, float* __restrict__ ph){
    int idx = blockIdx.x*256 + threadIdx.x;
    if (idx >= GG*256) return;
    int g = idx >> 8, j = idx & 255;
    float acc = b1[j];
    for (int k = 0; k < DD; k++) acc = fmaf(hg[g*DD + k], W1[k*256 + j], acc);
    ph[idx] = fmaxf(acc, 0.f);
}
__global__ void k_pred2(const float* __restrict__ ph, const float* __restrict__ W2,
                        const float* __restrict__ b2, float* __restrict__ out){
    int g = blockIdx.x*256 + threadIdx.x; if (g >= GG) return;
    float acc = b2[0];
    for (int k = 0; k < 256; k++) acc = fmaf(ph[g*256 + k], W2[k], acc);
    out[g] = acc;
}

extern "C" void kernel_launch(void* const* d_in, const int* in_sizes, int n_in,
                              void* d_out, int out_size, void* d_ws, size_t ws_size,
                              hipStream_t stream){
    float* out = (float*)d_out;
    const int OUT_N = GG + GG*DD + LL*GG*DD;      // 262656

    static const int EXP[24] = {50000,600000,600000,50000, 768,49152,384,49152,384,384,
                                49152,3,384,384,16384,128,128,16384,128,128,
                                32768,256,256,1};
    int bad = -1;
    if (n_in != 24) bad = 50;
    else for (int i = 0; i < 24; i++) if (in_sizes[i] != EXP[i]) { bad = i; break; }
    if (bad >= 0){
        k_mark<<<(OUT_N+255)/256, 256, 0, stream>>>(out, 2048.0f + (float)bad, OUT_N);
        return;
    }

    const int* d    = (const int*)d_in[0];
    const int* src  = (const int*)d_in[1];
    const int* dst  = (const int*)d_in[2];
    const int* bids = (const int*)d_in[3];
    const float* emb  = (const float*)d_in[4];
    const float* linW = (const float*)d_in[5];
    const float* linB = (const float*)d_in[6];
    const float* W1   = (const float*)d_in[7];
    const float* g1   = (const float*)d_in[8];
    const float* b1   = (const float*)d_in[9];
    const float* W2   = (const float*)d_in[10];
    const float* epsA = (const float*)d_in[11];
    const float* bng  = (const float*)d_in[12];
    const float* bnb  = (const float*)d_in[13];
    const float* pW1  = (const float*)d_in[14];
    const float* pg1  = (const float*)d_in[15];
    const float* pb1  = (const float*)d_in[16];
    const float* pW2  = (const float*)d_in[17];
    const float* pbng = (const float*)d_in[18];
    const float* pbnb = (const float*)d_in[19];
    const float* prW1 = (const float*)d_in[20];
    const float* prb1 = (const float*)d_in[21];
    const float* prW2 = (const float*)d_in[22];
    const float* prb2 = (const float*)d_in[23];

    // ---- workspace (~55 MB) ----
    float* x     = (float*)d_ws;                  // NN*DD  (h / z ping)
    float* y     = x + (size_t)NN*DD;             // NN*DD  (messages / t)
    float* stats = y + (size_t)NN*DD;             // 256
    float* ss1   = stats + 2*DD;                  // 256 (inner BN)
    float* ss2   = ss1 + 2*DD;                    // 256 (outer BN)
    float* hg    = ss2 + 2*DD;                    // GG*DD
    float* ph    = hg + (size_t)GG*DD;            // GG*256
    int* cnt    = (int*)(ph + (size_t)GG*256);
    int* inc    = cnt + NN;
    int* rowptr = inc + NN;                       // N+1
    int* cursor = rowptr + NN + 1;
    int* eidx   = cursor + NN;                    // E
    int* goff   = eidx + NE;                      // G+1
    int* bsum   = goff + GG + 1;                  // NB_SCAN
    int* boff   = bsum + NB_SCAN;                 // NB_SCAN+1

    float* out_pred   = out;
    float* out_hgraph = out + GG;
    float* out_hmeans = out + GG + GG*DD;

    const int NW_GRID  = (NN*DD + 255)/256;       // 25000
    const int E_GRID   = (NE + 255)/256;          // 2344
    const int AGG_GRID = (NN + 7)/8;              // 6250
    const int GEMM_GRID= (NN + 63)/64;            // 782

    // node features + graph boundaries + CSR (once)
    k_embed<<<NW_GRID, 256, 0, stream>>>(d, emb, x);
    k_goff<<<3, 256, 0, stream>>>(bids, goff);
    hipMemsetAsync(cnt, 0, NN*sizeof(int), stream);
    k_count<<<E_GRID, 256, 0, stream>>>(dst, cnt);
    k_scanA<<<NB_SCAN, 512, 0, stream>>>(cnt, inc, bsum);
    k_scanB<<<1, 64, 0, stream>>>(bsum, boff);
    k_scanC<<<NB_SCAN, 512, 0, stream>>>(cnt, inc, boff, rowptr, cursor);
    k_fill<<<E_GRID, 256, 0, stream>>>(src, dst, cursor, eidx);

    for (int l = 0; l < LL; l++){
        const float* lW = linW + (size_t)l*DD*DD;
        const float* lB = linB + (size_t)l*DD;
        const float* w1 = W1   + (size_t)l*DD*DD;
        const float* w2 = W2   + (size_t)l*DD*DD;

        // y = relu(x' @ lin_W + b), x' = relu(bn(x)) for l>0 (fused), raw embed for l=0
        if (l == 0)
            k_gemm<0,1,0><<<GEMM_GRID, 128, 0, stream>>>(x, lW, lB, nullptr, y, nullptr, NN);
        else
            k_gemm<2,1,0><<<GEMM_GRID, 128, 0, stream>>>(x, lW, lB, ss2, y, nullptr, NN);
        // x <- x'*(1+eps) + gather-sum(y)   (BN of self-term fused for l>0)
        k_agg<<<AGG_GRID, 256, 0, stream>>>(x, y, rowptr, eidx, epsA, l, (l == 0) ? nullptr : ss2);
        // y = x @ mlp_W1, fused column stats
        hipMemsetAsync(stats, 0, 2*DD*sizeof(float), stream);
        k_gemm<0,0,1><<<GEMM_GRID, 128, 0, stream>>>(x, w1, nullptr, nullptr, y, stats, NN);
        k_bnfin<<<1, 128, 0, stream>>>(stats, g1 + (size_t)l*DD, b1 + (size_t)l*DD, ss1);
        // x = relu(bn(y)) @ mlp_W2 (BN fused in staging), fused column stats of output
        hipMemsetAsync(stats, 0, 2*DD*sizeof(float), stream);
        k_gemm<2,0,1><<<GEMM_GRID, 128, 0, stream>>>(y, w2, nullptr, ss1, x, stats, NN);
        k_bnfin<<<1, 128, 0, stream>>>(stats, bng + (size_t)l*DD, bnb + (size_t)l*DD, ss2);
        // h_means[l] = mean_g relu(bn(x))  (BN fused in pool)
        k_poolbn<<<GG, 128, 0, stream>>>(x, ss2, goff, out_hmeans + (size_t)l*GG*DD, nullptr);
    }

    // pooling MLP: p = relu(bn(x' @ pool_W1)) @ pool_W2 ; h_graph = mean_g relu(bn(p))
    hipMemsetAsync(stats, 0, 2*DD*sizeof(float), stream);
    k_gemm<2,0,1><<<GEMM_GRID, 128, 0, stream>>>(x, pW1, nullptr, ss2, y, stats, NN);
    k_bnfin<<<1, 128, 0, stream>>>(stats, pg1, pb1, ss1);
    hipMemsetAsync(stats, 0, 2*DD*sizeof(float), stream);
    k_gemm<2,0,1><<<GEMM_GRID, 128, 0, stream>>>(y, pW2, nullptr, ss1, x, stats, NN);
    k_bnfin<<<1, 128, 0, stream>>>(stats, pbng, pbnb, ss2);
    k_poolbn<<<GG, 128, 0, stream>>>(x, ss2, goff, out_hgraph, hg);
    // predict
    k_pred1<<<GG, 256, 0, stream>>>(hg, prW1, prb1, ph);
    k_pred2<<<2, 256, 0, stream>>>(ph, prW2, prb2, out_pred);
}

// Round 8
// 808.643 us; speedup vs baseline: 3.7437x; 1.0912x over previous
//
#include <hip/hip_runtime.h>

typedef unsigned short ushort_t;
typedef __attribute__((ext_vector_type(8))) short bf16x8;
typedef __attribute__((ext_vector_type(4))) float f32x4;

#define NN 50000
#define NE 600000
#define DD 128
#define LL 3
#define GG 512
#define NB_SCAN 98   // ceil(NN/512)

__device__ __forceinline__ float b2f(ushort_t u){ return __uint_as_float(((unsigned)u)<<16); }
__device__ __forceinline__ ushort_t f2b(float f){
    unsigned x = __float_as_uint(f);
    return (ushort_t)((x + 0x7fffu + ((x>>16)&1u)) >> 16);
}

// ---- marker for host-side input-layout mismatch (f32 out) ----
__global__ void k_mark(float* __restrict__ out, float val, int n){
    int i = blockIdx.x*256 + threadIdx.x; if (i >= n) return;
    out[i] = (i == 0) ? val : 0.f;
}

// ---- weights: fp32 [k][n] -> bf16 transposed [n][k], 11 matrices ----
struct WPtrs { const float* p[11]; };
__global__ void k_wconv(WPtrs wp, ushort_t* __restrict__ Wt){
    int idx = blockIdx.x*256 + threadIdx.x;   // 11*16384
    if (idx >= 11*16384) return;
    int m = idx >> 14, r = idx & 16383;
    int n = r >> 7, k = r & 127;
    Wt[idx] = f2b(wp.p[m][k*DD + n]);
}

// ---------------- embed -> bf16 ----------------
__global__ void k_embed(const int* __restrict__ d, const float* __restrict__ tab,
                        ushort_t* __restrict__ xb){
    int idx = blockIdx.x*256 + threadIdx.x;
    if (idx >= NN*DD) return;
    int row = idx >> 7, c = idx & 127;
    int di = d[row]; di = di < 0 ? 0 : (di > 5 ? 5 : di);
    xb[idx] = f2b(tab[di*DD + c]);
}

// ---------------- group offsets ----------------
__global__ void k_goff(const int* __restrict__ bids, int* __restrict__ goff){
    int g = blockIdx.x*256 + threadIdx.x;
    if (g > GG) return;
    int lo = 0, hi = NN;
    while (lo < hi){ int mid = (lo+hi) >> 1; if (bids[mid] < g) lo = mid+1; else hi = mid; }
    goff[g] = lo;
}

// ---------------- CSR build ----------------
__global__ void k_count(const int* __restrict__ dst, int* __restrict__ cnt){
    int e = blockIdx.x*256 + threadIdx.x; if (e >= NE) return;
    atomicAdd(&cnt[dst[e]], 1);
}
__global__ void k_scanA(const int* __restrict__ cnt, int* __restrict__ inc, int* __restrict__ bsum){
    __shared__ int s[512];
    int i = blockIdx.x*512 + threadIdx.x;
    int v = (i < NN) ? cnt[i] : 0;
    s[threadIdx.x] = v; __syncthreads();
    for (int off = 1; off < 512; off <<= 1){
        int add = (threadIdx.x >= off) ? s[threadIdx.x - off] : 0;
        __syncthreads();
        s[threadIdx.x] += add;
        __syncthreads();
    }
    if (i < NN) inc[i] = s[threadIdx.x];
    if (threadIdx.x == 511) bsum[blockIdx.x] = s[511];
}
__global__ void k_scanB(const int* __restrict__ bsum, int* __restrict__ boff){
    if (threadIdx.x == 0 && blockIdx.x == 0){
        int acc = 0;
        for (int b = 0; b < NB_SCAN; b++){ boff[b] = acc; acc += bsum[b]; }
        boff[NB_SCAN] = acc;
    }
}
__global__ void k_scanC(const int* __restrict__ cnt, const int* __restrict__ inc,
                        const int* __restrict__ boff, int* __restrict__ rowptr,
                        int* __restrict__ cursor){
    int i = blockIdx.x*512 + threadIdx.x;
    if (i < NN){
        int e = boff[blockIdx.x] + inc[i] - cnt[i];
        rowptr[i] = e; cursor[i] = e;
    } else if (i == NN){
        rowptr[NN] = NE;
    }
}
__global__ void k_fill(const int* __restrict__ src, const int* __restrict__ dst,
                       int* __restrict__ cursor, int* __restrict__ eidx){
    int e = blockIdx.x*256 + threadIdx.x; if (e >= NE) return;
    int p = atomicAdd(&cursor[dst[e]], 1);
    eidx[p] = src[e];
}

// ---- aggregation (bf16 in/out): zb[v] = f(xb[v])*(1+eps) + sum gather yb[src] ----
__global__ void k_agg(const ushort_t* __restrict__ xb, const ushort_t* __restrict__ yb,
                      ushort_t* __restrict__ zb,
                      const int* __restrict__ rowptr, const int* __restrict__ eidx,
                      const float* __restrict__ epsP, int l, const float* __restrict__ ss){
    int node = blockIdx.x*8 + (threadIdx.x >> 5);
    if (node >= NN) return;
    int c4 = (threadIdx.x & 31) << 2;
    float epl = 1.0f + epsP[l];
    ushort4 xr = *(const ushort4*)(xb + (size_t)node*DD + c4);
    float a0 = b2f(xr.x), a1 = b2f(xr.y), a2 = b2f(xr.z), a3 = b2f(xr.w);
    if (ss){
        a0 = fmaxf(fmaf(a0, ss[c4+0], ss[DD+c4+0]), 0.f);
        a1 = fmaxf(fmaf(a1, ss[c4+1], ss[DD+c4+1]), 0.f);
        a2 = fmaxf(fmaf(a2, ss[c4+2], ss[DD+c4+2]), 0.f);
        a3 = fmaxf(fmaf(a3, ss[c4+3], ss[DD+c4+3]), 0.f);
    }
    a0 *= epl; a1 *= epl; a2 *= epl; a3 *= epl;
    int e0 = rowptr[node], e1 = rowptr[node+1];
    for (int e = e0; e < e1; e++){
        int s = eidx[e];
        ushort4 v = *(const ushort4*)(yb + (size_t)s*DD + c4);
        a0 += b2f(v.x); a1 += b2f(v.y); a2 += b2f(v.z); a3 += b2f(v.w);
    }
    ushort4 o; o.x = f2b(a0); o.y = f2b(a1); o.z = f2b(a2); o.w = f2b(a3);
    *(ushort4*)(zb + (size_t)node*DD + c4) = o;
}

// ---------------- bn finalize ----------------
__global__ void k_bnfin(const float* __restrict__ stats, const float* __restrict__ g,
                        const float* __restrict__ b, float* __restrict__ ss){
    int c = threadIdx.x; if (c >= DD) return;
    float mu  = stats[c] * (1.0f/NN);
    float var = stats[c + DD] * (1.0f/NN) - mu*mu;
    float sc  = rsqrtf(fmaxf(var, 0.f) + 1e-5f) * g[c];
    ss[c] = sc;
    ss[c + DD] = b[c] - mu*sc;
}

// ---------------- MFMA GEMM: C[M,128] = op(A') @ W  (bf16 in/out, fp32 accum) ----
// A bf16 [M][128]; Wt bf16 [n][k] transposed, L2-resident -> B-frags direct, no LDS staging.
// AMODE: 0 plain; 2 A'=relu(A*sc+sh). OMODE: 0 plain; 1 relu(C+bias). STATS: column sum/sumsq.
template<int AMODE, int OMODE, int STATS>
__global__ __launch_bounds__(256) void k_gemm(
    const ushort_t* __restrict__ A, const ushort_t* __restrict__ Wt,
    const float* __restrict__ bias, const float* __restrict__ ss,
    ushort_t* __restrict__ C, float* __restrict__ stats, int M)
{
    __shared__ float sred[256];
    const int t = threadIdx.x;
    const int w = t >> 6;                    // wave 0..3
    const int l = t & 63;
    const int rowBase = blockIdx.x * 64 + w * 16;
    const int lm = l & 15;                   // A-row / B-col / D-col within tile
    const int kg = l >> 4;                   // k-group 0..3

    if (STATS){ sred[t] = 0.f; __syncthreads(); }

    f32x4 acc[8];
#pragma unroll
    for (int n = 0; n < 8; n++) acc[n] = (f32x4){0.f,0.f,0.f,0.f};

    int arow = rowBase + lm;
    if (arow >= M) arow = M - 1;             // clamp; pad rows masked at store/stats
    const ushort_t* aptr = A + (size_t)arow*DD + kg*8;

#pragma unroll
    for (int s = 0; s < 4; s++){
        bf16x8 af;
        if (AMODE == 0){
            af = *(const bf16x8*)(aptr + s*32);
        } else {
            bf16x8 ar = *(const bf16x8*)(aptr + s*32);
            int k0 = s*32 + kg*8;
#pragma unroll
            for (int i = 0; i < 8; i++){
                float v = b2f((ushort_t)ar[i]);
                v = fmaxf(fmaf(v, ss[k0+i], ss[DD+k0+i]), 0.f);
                ((ushort_t*)&af)[i] = f2b(v);
            }
        }
#pragma unroll
        for (int n = 0; n < 8; n++){
            bf16x8 bfr = *(const bf16x8*)(Wt + (size_t)(n*16 + lm)*DD + s*32 + kg*8);
            acc[n] = __builtin_amdgcn_mfma_f32_16x16x32_bf16(af, bfr, acc[n], 0, 0, 0);
        }
    }

    // D layout: tile n -> col = n*16 + lm, rows rowBase + kg*4 + j
#pragma unroll
    for (int n = 0; n < 8; n++){
        int col = n*16 + lm;
        float cs = 0.f, cq = 0.f;
#pragma unroll
        for (int j = 0; j < 4; j++){
            int row = rowBase + kg*4 + j;
            float v = acc[n][j];
            if (OMODE == 1) v = fmaxf(v + bias[col], 0.f);
            if (row < M){
                C[(size_t)row*DD + col] = f2b(v);
                if (STATS){ cs += v; cq += v*v; }
            }
        }
        if (STATS){
            cs += __shfl_xor(cs, 16); cs += __shfl_xor(cs, 32);
            cq += __shfl_xor(cq, 16); cq += __shfl_xor(cq, 32);
            if (kg == 0){
                atomicAdd(&sred[col], cs);
                atomicAdd(&sred[col + DD], cq);
            }
        }
    }
    if (STATS){
        __syncthreads();
        atomicAdd(&stats[t], sred[t]);
    }
}

// ---------------- pooling with fused BN+ReLU (bf16 in, f32 out) ----------------
__global__ void k_poolbn(const ushort_t* __restrict__ h, const float* __restrict__ ss,
                         const int* __restrict__ goff, float* __restrict__ outp,
                         float* __restrict__ outf){
    int g = blockIdx.x;
    int c = threadIdx.x;           // 128 threads
    float sc = ss[c], sh = ss[DD + c];
    int r0 = goff[g], r1 = goff[g+1];
    float acc = 0.f;
    for (int r = r0; r < r1; r++)
        acc += fmaxf(fmaf(b2f(h[(size_t)r*DD + c]), sc, sh), 0.f);
    float m = acc / fmaxf((float)(r1 - r0), 1.0f);
    outp[g*DD + c] = m;
    if (outf) outf[g*DD + c] = m;
}

// ---------------- predict head (fp32) ----------------
__global__ void k_pred1(const float* __restrict__ hg, const float* __restrict__ W1,
                        const float* __restrict__ b1, float* __restrict__ ph){
    int idx = blockIdx.x*256 + threadIdx.x;
    if (idx >= GG*256) return;
    int g = idx >> 8, j = idx & 255;
    float acc = b1[j];
    for (int k = 0; k < DD; k++) acc = fmaf(hg[g*DD + k], W1[k*256 + j], acc);
    ph[idx] = fmaxf(acc, 0.f);
}
__global__ void k_pred2(const float* __restrict__ ph, const float* __restrict__ W2,
                        const float* __restrict__ b2, float* __restrict__ out){
    int g = blockIdx.x*256 + threadIdx.x; if (g >= GG) return;
    float acc = b2[0];
    for (int k = 0; k < 256; k++) acc = fmaf(ph[g*256 + k], W2[k], acc);
    out[g] = acc;
}

extern "C" void kernel_launch(void* const* d_in, const int* in_sizes, int n_in,
                              void* d_out, int out_size, void* d_ws, size_t ws_size,
                              hipStream_t stream){
    float* out = (float*)d_out;
    const int OUT_N = GG + GG*DD + LL*GG*DD;      // 262656

    static const int EXP[24] = {50000,600000,600000,50000, 768,49152,384,49152,384,384,
                                49152,3,384,384,16384,128,128,16384,128,128,
                                32768,256,256,1};
    int bad = -1;
    if (n_in != 24) bad = 50;
    else for (int i = 0; i < 24; i++) if (in_sizes[i] != EXP[i]) { bad = i; break; }
    if (bad >= 0){
        k_mark<<<(OUT_N+255)/256, 256, 0, stream>>>(out, 2048.0f + (float)bad, OUT_N);
        return;
    }

    const int* d    = (const int*)d_in[0];
    const int* src  = (const int*)d_in[1];
    const int* dst  = (const int*)d_in[2];
    const int* bids = (const int*)d_in[3];
    const float* emb  = (const float*)d_in[4];
    const float* linW = (const float*)d_in[5];
    const float* linB = (const float*)d_in[6];
    const float* W1   = (const float*)d_in[7];
    const float* g1   = (const float*)d_in[8];
    const float* b1   = (const float*)d_in[9];
    const float* W2   = (const float*)d_in[10];
    const float* epsA = (const float*)d_in[11];
    const float* bng  = (const float*)d_in[12];
    const float* bnb  = (const float*)d_in[13];
    const float* pW1  = (const float*)d_in[14];
    const float* pg1  = (const float*)d_in[15];
    const float* pb1  = (const float*)d_in[16];
    const float* pW2  = (const float*)d_in[17];
    const float* pbng = (const float*)d_in[18];
    const float* pbnb = (const float*)d_in[19];
    const float* prW1 = (const float*)d_in[20];
    const float* prb1 = (const float*)d_in[21];
    const float* prW2 = (const float*)d_in[22];
    const float* prb2 = (const float*)d_in[23];

    // ---- workspace (~45 MB) ----
    ushort_t* xb  = (ushort_t*)d_ws;              // NN*DD bf16
    ushort_t* yb  = xb + (size_t)NN*DD;
    ushort_t* zb  = yb + (size_t)NN*DD;
    ushort_t* Wt  = zb + (size_t)NN*DD;           // 11*16384 bf16 (transposed weights)
    float* stats = (float*)(Wt + 11*16384);       // 256
    float* ss1   = stats + 2*DD;                  // 256
    float* ss2   = ss1 + 2*DD;                    // 256
    float* hg    = ss2 + 2*DD;                    // GG*DD
    float* ph    = hg + (size_t)GG*DD;            // GG*256
    int* cnt    = (int*)(ph + (size_t)GG*256);
    int* inc    = cnt + NN;
    int* rowptr = inc + NN;                       // N+1
    int* cursor = rowptr + NN + 1;
    int* eidx   = cursor + NN;                    // E
    int* goff   = eidx + NE;                      // G+1
    int* bsum   = goff + GG + 1;
    int* boff   = bsum + NB_SCAN;

    float* out_pred   = out;
    float* out_hgraph = out + GG;
    float* out_hmeans = out + GG + GG*DD;

    const int NW_GRID  = (NN*DD + 255)/256;       // 25000
    const int E_GRID   = (NE + 255)/256;          // 2344
    const int AGG_GRID = (NN + 7)/8;              // 6250
    const int GEMM_GRID= (NN + 63)/64;            // 782

    // weight convert/transpose (11 matrices -> bf16 [n][k])
    WPtrs wp;
    for (int i = 0; i < 3; i++){
        wp.p[i]   = linW + (size_t)i*DD*DD;
        wp.p[3+i] = W1   + (size_t)i*DD*DD;
        wp.p[6+i] = W2   + (size_t)i*DD*DD;
    }
    wp.p[9] = pW1; wp.p[10] = pW2;
    k_wconv<<<(11*16384 + 255)/256, 256, 0, stream>>>(wp, Wt);
    const ushort_t* WtLin = Wt;
    const ushort_t* WtW1  = Wt + 3*16384;
    const ushort_t* WtW2  = Wt + 6*16384;
    const ushort_t* WtPW1 = Wt + 9*16384;
    const ushort_t* WtPW2 = Wt + 10*16384;

    // node features + graph boundaries + CSR (once)
    k_embed<<<NW_GRID, 256, 0, stream>>>(d, emb, xb);
    k_goff<<<3, 256, 0, stream>>>(bids, goff);
    hipMemsetAsync(cnt, 0, NN*sizeof(int), stream);
    k_count<<<E_GRID, 256, 0, stream>>>(dst, cnt);
    k_scanA<<<NB_SCAN, 512, 0, stream>>>(cnt, inc, bsum);
    k_scanB<<<1, 64, 0, stream>>>(bsum, boff);
    k_scanC<<<NB_SCAN, 512, 0, stream>>>(cnt, inc, boff, rowptr, cursor);
    k_fill<<<E_GRID, 256, 0, stream>>>(src, dst, cursor, eidx);

    for (int l = 0; l < LL; l++){
        // yb = relu(A' @ lin_W + b), A' = relu(bn(xb)) for l>0
        if (l == 0)
            k_gemm<0,1,0><<<GEMM_GRID, 256, 0, stream>>>(xb, WtLin + (size_t)l*16384, linB + (size_t)l*DD, nullptr, yb, nullptr, NN);
        else
            k_gemm<2,1,0><<<GEMM_GRID, 256, 0, stream>>>(xb, WtLin + (size_t)l*16384, linB + (size_t)l*DD, ss2, yb, nullptr, NN);
        // zb = A'*(1+eps) + gather(yb)
        k_agg<<<AGG_GRID, 256, 0, stream>>>(xb, yb, zb, rowptr, eidx, epsA, l, (l == 0) ? nullptr : ss2);
        // yb = zb @ mlp_W1 (+stats)
        hipMemsetAsync(stats, 0, 2*DD*sizeof(float), stream);
        k_gemm<0,0,1><<<GEMM_GRID, 256, 0, stream>>>(zb, WtW1 + (size_t)l*16384, nullptr, nullptr, yb, stats, NN);
        k_bnfin<<<1, 128, 0, stream>>>(stats, g1 + (size_t)l*DD, b1 + (size_t)l*DD, ss1);
        // xb = relu(bn(yb)) @ mlp_W2 (+stats)
        hipMemsetAsync(stats, 0, 2*DD*sizeof(float), stream);
        k_gemm<2,0,1><<<GEMM_GRID, 256, 0, stream>>>(yb, WtW2 + (size_t)l*16384, nullptr, ss1, xb, stats, NN);
        k_bnfin<<<1, 128, 0, stream>>>(stats, bng + (size_t)l*DD, bnb + (size_t)l*DD, ss2);
        // h_means[l] = mean_g relu(bn(xb))
        k_poolbn<<<GG, 128, 0, stream>>>(xb, ss2, goff, out_hmeans + (size_t)l*GG*DD, nullptr);
    }

    // pooling MLP
    hipMemsetAsync(stats, 0, 2*DD*sizeof(float), stream);
    k_gemm<2,0,1><<<GEMM_GRID, 256, 0, stream>>>(xb, WtPW1, nullptr, ss2, yb, stats, NN);
    k_bnfin<<<1, 128, 0, stream>>>(stats, pg1, pb1, ss1);
    hipMemsetAsync(stats, 0, 2*DD*sizeof(float), stream);
    k_gemm<2,0,1><<<GEMM_GRID, 256, 0, stream>>>(yb, WtPW2, nullptr, ss1, zb, stats, NN);
    k_bnfin<<<1, 128, 0, stream>>>(stats, pbng, pbnb, ss2);
    k_poolbn<<<GG, 128, 0, stream>>>(zb, ss2, goff, out_hgraph, hg);
    // predict
    k_pred1<<<GG, 256, 0, stream>>>(hg, prW1, prb1, ph);
    k_pred2<<<2, 256, 0, stream>>>(ph, prW2, prb2, out_pred);
}

// Round 9
// 674.795 us; speedup vs baseline: 4.4863x; 1.1984x over previous
//
#include <hip/hip_runtime.h>

typedef unsigned short ushort_t;
typedef __attribute__((ext_vector_type(8))) short bf16x8;
typedef __attribute__((ext_vector_type(4))) float f32x4;

#define NN 50000
#define NE 600000
#define DD 128
#define LL 3
#define GG 512
#define NB_SCAN 98   // ceil(NN/512)

__device__ __forceinline__ float b2f(ushort_t u){ return __uint_as_float(((unsigned)u)<<16); }
__device__ __forceinline__ ushort_t f2b(float f){
    unsigned x = __float_as_uint(f);
    return (ushort_t)((x + 0x7fffu + ((x>>16)&1u)) >> 16);
}

// ---- marker for host-side input-layout mismatch (f32 out) ----
__global__ void k_mark(float* __restrict__ out, float val, int n){
    int i = blockIdx.x*256 + threadIdx.x; if (i >= n) return;
    out[i] = (i == 0) ? val : 0.f;
}

// ---- weights: fp32 [k][n] -> bf16 in MFMA B-FRAGMENT order ----
// Wf[m][n][s][lane][i]: k = s*32 + (lane>>4)*8 + i, col = n*16 + (lane&15)
struct WPtrs { const float* p[11]; };
__global__ void k_wconv(WPtrs wp, ushort_t* __restrict__ Wf){
    int idx = blockIdx.x*256 + threadIdx.x;   // 11*16384
    if (idx >= 11*16384) return;
    int m = idx >> 14, r = idx & 16383;
    int i = r & 7, l = (r >> 3) & 63, s = (r >> 9) & 3, n = r >> 11;
    int k   = s*32 + (l >> 4)*8 + i;
    int col = n*16 + (l & 15);
    Wf[idx] = f2b(wp.p[m][k*DD + col]);
}

// ---------------- embed -> bf16 ----------------
__global__ void k_embed(const int* __restrict__ d, const float* __restrict__ tab,
                        ushort_t* __restrict__ xb){
    int idx = blockIdx.x*256 + threadIdx.x;
    if (idx >= NN*DD) return;
    int row = idx >> 7, c = idx & 127;
    int di = d[row]; di = di < 0 ? 0 : (di > 5 ? 5 : di);
    xb[idx] = f2b(tab[di*DD + c]);
}

// ---------------- group offsets ----------------
__global__ void k_goff(const int* __restrict__ bids, int* __restrict__ goff){
    int g = blockIdx.x*256 + threadIdx.x;
    if (g > GG) return;
    int lo = 0, hi = NN;
    while (lo < hi){ int mid = (lo+hi) >> 1; if (bids[mid] < g) lo = mid+1; else hi = mid; }
    goff[g] = lo;
}

// ---------------- CSR build ----------------
__global__ void k_count(const int* __restrict__ dst, int* __restrict__ cnt){
    int e = blockIdx.x*256 + threadIdx.x; if (e >= NE) return;
    atomicAdd(&cnt[dst[e]], 1);
}
__global__ void k_scanA(const int* __restrict__ cnt, int* __restrict__ inc, int* __restrict__ bsum){
    __shared__ int s[512];
    int i = blockIdx.x*512 + threadIdx.x;
    int v = (i < NN) ? cnt[i] : 0;
    s[threadIdx.x] = v; __syncthreads();
    for (int off = 1; off < 512; off <<= 1){
        int add = (threadIdx.x >= off) ? s[threadIdx.x - off] : 0;
        __syncthreads();
        s[threadIdx.x] += add;
        __syncthreads();
    }
    if (i < NN) inc[i] = s[threadIdx.x];
    if (threadIdx.x == 511) bsum[blockIdx.x] = s[511];
}
__global__ void k_scanB(const int* __restrict__ bsum, int* __restrict__ boff){
    if (threadIdx.x == 0 && blockIdx.x == 0){
        int acc = 0;
        for (int b = 0; b < NB_SCAN; b++){ boff[b] = acc; acc += bsum[b]; }
        boff[NB_SCAN] = acc;
    }
}
__global__ void k_scanC(const int* __restrict__ cnt, const int* __restrict__ inc,
                        const int* __restrict__ boff, int* __restrict__ rowptr,
                        int* __restrict__ cursor){
    int i = blockIdx.x*512 + threadIdx.x;
    if (i < NN){
        int e = boff[blockIdx.x] + inc[i] - cnt[i];
        rowptr[i] = e; cursor[i] = e;
    } else if (i == NN){
        rowptr[NN] = NE;
    }
}
__global__ void k_fill(const int* __restrict__ src, const int* __restrict__ dst,
                       int* __restrict__ cursor, int* __restrict__ eidx){
    int e = blockIdx.x*256 + threadIdx.x; if (e >= NE) return;
    int p = atomicAdd(&cursor[dst[e]], 1);
    eidx[p] = src[e];
}

// ---- aggregation: 16 lanes/node, bf16x8 loads, 4 independent chains per wave ----
__global__ void k_agg(const ushort_t* __restrict__ xb, const ushort_t* __restrict__ yb,
                      ushort_t* __restrict__ zb,
                      const int* __restrict__ rowptr, const int* __restrict__ eidx,
                      const float* __restrict__ epsP, int l, const float* __restrict__ ss){
    int node = blockIdx.x*16 + (threadIdx.x >> 4);
    if (node >= NN) return;
    int c8 = (threadIdx.x & 15) << 3;
    float epl = 1.0f + epsP[l];
    bf16x8 xr = *(const bf16x8*)(xb + (size_t)node*DD + c8);
    float a[8];
#pragma unroll
    for (int i = 0; i < 8; i++) a[i] = b2f((ushort_t)xr[i]);
    if (ss){
#pragma unroll
        for (int i = 0; i < 8; i++)
            a[i] = fmaxf(fmaf(a[i], ss[c8+i], ss[DD+c8+i]), 0.f);
    }
#pragma unroll
    for (int i = 0; i < 8; i++) a[i] *= epl;
    int e0 = rowptr[node], e1 = rowptr[node+1];
    for (int e = e0; e < e1; e++){
        int s = eidx[e];
        bf16x8 v = *(const bf16x8*)(yb + (size_t)s*DD + c8);
#pragma unroll
        for (int i = 0; i < 8; i++) a[i] += b2f((ushort_t)v[i]);
    }
    bf16x8 o;
#pragma unroll
    for (int i = 0; i < 8; i++) o[i] = (short)f2b(a[i]);
    *(bf16x8*)(zb + (size_t)node*DD + c8) = o;
}

// ---------------- bn finalize ----------------
__global__ void k_bnfin(const float* __restrict__ stats, const float* __restrict__ g,
                        const float* __restrict__ b, float* __restrict__ ss){
    int c = threadIdx.x; if (c >= DD) return;
    float mu  = stats[c] * (1.0f/NN);
    float var = stats[c + DD] * (1.0f/NN) - mu*mu;
    float sc  = rsqrtf(fmaxf(var, 0.f) + 1e-5f) * g[c];
    ss[c] = sc;
    ss[c + DD] = b[c] - mu*sc;
}

// ---------------- MFMA GEMM: C[M,128] = op(A') @ W  (bf16, fp32 accum) ----
// Wf in fragment order: frag(n,s) at Wf + ((n*4+s)*64 + lane)*8 -> coalesced 1KB/wave
template<int AMODE, int OMODE, int STATS>
__global__ __launch_bounds__(256) void k_gemm(
    const ushort_t* __restrict__ A, const ushort_t* __restrict__ Wf,
    const float* __restrict__ bias, const float* __restrict__ ss,
    ushort_t* __restrict__ C, float* __restrict__ stats, int M)
{
    __shared__ float sred[256];
    const int t = threadIdx.x;
    const int w = t >> 6;                    // wave 0..3
    const int l = t & 63;
    const int rowBase = blockIdx.x * 64 + w * 16;
    const int lm = l & 15;
    const int kg = l >> 4;

    if (STATS){ sred[t] = 0.f; __syncthreads(); }

    f32x4 acc[8];
#pragma unroll
    for (int n = 0; n < 8; n++) acc[n] = (f32x4){0.f,0.f,0.f,0.f};

    int arow = rowBase + lm;
    if (arow >= M) arow = M - 1;             // clamp; pad rows masked at store/stats
    const ushort_t* aptr = A + (size_t)arow*DD + kg*8;

#pragma unroll
    for (int s = 0; s < 4; s++){
        bf16x8 af;
        if (AMODE == 0){
            af = *(const bf16x8*)(aptr + s*32);
        } else {
            bf16x8 ar = *(const bf16x8*)(aptr + s*32);
            int k0 = s*32 + kg*8;
#pragma unroll
            for (int i = 0; i < 8; i++){
                float v = b2f((ushort_t)ar[i]);
                v = fmaxf(fmaf(v, ss[k0+i], ss[DD+k0+i]), 0.f);
                ((ushort_t*)&af)[i] = f2b(v);
            }
        }
#pragma unroll
        for (int n = 0; n < 8; n++){
            bf16x8 bfr = *(const bf16x8*)(Wf + (size_t)((n*4 + s)*64 + l)*8);
            acc[n] = __builtin_amdgcn_mfma_f32_16x16x32_bf16(af, bfr, acc[n], 0, 0, 0);
        }
    }

    // D layout: tile n -> col = n*16 + lm, rows rowBase + kg*4 + j
#pragma unroll
    for (int n = 0; n < 8; n++){
        int col = n*16 + lm;
        float cs = 0.f, cq = 0.f;
#pragma unroll
        for (int j = 0; j < 4; j++){
            int row = rowBase + kg*4 + j;
            float v = acc[n][j];
            if (OMODE == 1) v = fmaxf(v + bias[col], 0.f);
            if (row < M){
                C[(size_t)row*DD + col] = f2b(v);
                if (STATS){ cs += v; cq += v*v; }
            }
        }
        if (STATS){
            cs += __shfl_xor(cs, 16); cs += __shfl_xor(cs, 32);
            cq += __shfl_xor(cq, 16); cq += __shfl_xor(cq, 32);
            if (kg == 0){
                atomicAdd(&sred[col], cs);
                atomicAdd(&sred[col + DD], cq);
            }
        }
    }
    if (STATS){
        __syncthreads();
        atomicAdd(&stats[t], sred[t]);
    }
}

// ---------------- pooling with fused BN+ReLU (bf16 in, f32 out) ----------------
__global__ void k_poolbn(const ushort_t* __restrict__ h, const float* __restrict__ ss,
                         const int* __restrict__ goff, float* __restrict__ outp,
                         float* __restrict__ outf){
    int g = blockIdx.x;
    int c = threadIdx.x;           // 128 threads
    float sc = ss[c], sh = ss[DD + c];
    int r0 = goff[g], r1 = goff[g+1];
    float acc = 0.f;
    for (int r = r0; r < r1; r++)
        acc += fmaxf(fmaf(b2f(h[(size_t)r*DD + c]), sc, sh), 0.f);
    float m = acc / fmaxf((float)(r1 - r0), 1.0f);
    outp[g*DD + c] = m;
    if (outf) outf[g*DD + c] = m;
}

// ---------------- predict head (fp32) ----------------
__global__ void k_pred1(const float* __restrict__ hg, const float* __restrict__ W1,
                        const float* __restrict__ b1, float* __restrict__ ph){
    int idx = blockIdx.x*256 + threadIdx.x;
    if (idx >= GG*256) return;
    int g = idx >> 8, j = idx & 255;
    float acc = b1[j];
    for (int k = 0; k < DD; k++) acc = fmaf(hg[g*DD + k], W1[k*256 + j], acc);
    ph[idx] = fmaxf(acc, 0.f);
}
__global__ void k_pred2(const float* __restrict__ ph, const float* __restrict__ W2,
                        const float* __restrict__ b2, float* __restrict__ out){
    int g = blockIdx.x*256 + threadIdx.x; if (g >= GG) return;
    float acc = b2[0];
    for (int k = 0; k < 256; k++) acc = fmaf(ph[g*256 + k], W2[k], acc);
    out[g] = acc;
}

extern "C" void kernel_launch(void* const* d_in, const int* in_sizes, int n_in,
                              void* d_out, int out_size, void* d_ws, size_t ws_size,
                              hipStream_t stream){
    float* out = (float*)d_out;
    const int OUT_N = GG + GG*DD + LL*GG*DD;      // 262656

    static const int EXP[24] = {50000,600000,600000,50000, 768,49152,384,49152,384,384,
                                49152,3,384,384,16384,128,128,16384,128,128,
                                32768,256,256,1};
    int bad = -1;
    if (n_in != 24) bad = 50;
    else for (int i = 0; i < 24; i++) if (in_sizes[i] != EXP[i]) { bad = i; break; }
    if (bad >= 0){
        k_mark<<<(OUT_N+255)/256, 256, 0, stream>>>(out, 2048.0f + (float)bad, OUT_N);
        return;
    }

    const int* d    = (const int*)d_in[0];
    const int* src  = (const int*)d_in[1];
    const int* dst  = (const int*)d_in[2];
    const int* bids = (const int*)d_in[3];
    const float* emb  = (const float*)d_in[4];
    const float* linW = (const float*)d_in[5];
    const float* linB = (const float*)d_in[6];
    const float* W1   = (const float*)d_in[7];
    const float* g1   = (const float*)d_in[8];
    const float* b1   = (const float*)d_in[9];
    const float* W2   = (const float*)d_in[10];
    const float* epsA = (const float*)d_in[11];
    const float* bng  = (const float*)d_in[12];
    const float* bnb  = (const float*)d_in[13];
    const float* pW1  = (const float*)d_in[14];
    const float* pg1  = (const float*)d_in[15];
    const float* pb1  = (const float*)d_in[16];
    const float* pW2  = (const float*)d_in[17];
    const float* pbng = (const float*)d_in[18];
    const float* pbnb = (const float*)d_in[19];
    const float* prW1 = (const float*)d_in[20];
    const float* prb1 = (const float*)d_in[21];
    const float* prW2 = (const float*)d_in[22];
    const float* prb2 = (const float*)d_in[23];

    // ---- workspace (~45 MB) ----
    ushort_t* xb  = (ushort_t*)d_ws;              // NN*DD bf16
    ushort_t* yb  = xb + (size_t)NN*DD;
    ushort_t* zb  = yb + (size_t)NN*DD;
    ushort_t* Wf  = zb + (size_t)NN*DD;           // 11*16384 bf16 (fragment-ordered)
    float* stats = (float*)(Wf + 11*16384);       // 256
    float* ss1   = stats + 2*DD;                  // 256
    float* ss2   = ss1 + 2*DD;                    // 256
    float* hg    = ss2 + 2*DD;                    // GG*DD
    float* ph    = hg + (size_t)GG*DD;            // GG*256
    int* cnt    = (int*)(ph + (size_t)GG*256);
    int* inc    = cnt + NN;
    int* rowptr = inc + NN;                       // N+1
    int* cursor = rowptr + NN + 1;
    int* eidx   = cursor + NN;                    // E
    int* goff   = eidx + NE;                      // G+1
    int* bsum   = goff + GG + 1;
    int* boff   = bsum + NB_SCAN;

    float* out_pred   = out;
    float* out_hgraph = out + GG;
    float* out_hmeans = out + GG + GG*DD;

    const int NW_GRID  = (NN*DD + 255)/256;       // 25000
    const int E_GRID   = (NE + 255)/256;          // 2344
    const int AGG_GRID = (NN + 15)/16;            // 3125
    const int GEMM_GRID= (NN + 63)/64;            // 782

    // weight convert -> fragment order
    WPtrs wp;
    for (int i = 0; i < 3; i++){
        wp.p[i]   = linW + (size_t)i*DD*DD;
        wp.p[3+i] = W1   + (size_t)i*DD*DD;
        wp.p[6+i] = W2   + (size_t)i*DD*DD;
    }
    wp.p[9] = pW1; wp.p[10] = pW2;
    k_wconv<<<(11*16384 + 255)/256, 256, 0, stream>>>(wp, Wf);
    const ushort_t* WfLin = Wf;
    const ushort_t* WfW1  = Wf + 3*16384;
    const ushort_t* WfW2  = Wf + 6*16384;
    const ushort_t* WfPW1 = Wf + 9*16384;
    const ushort_t* WfPW2 = Wf + 10*16384;

    // node features + graph boundaries + CSR (once)
    k_embed<<<NW_GRID, 256, 0, stream>>>(d, emb, xb);
    k_goff<<<3, 256, 0, stream>>>(bids, goff);
    hipMemsetAsync(cnt, 0, NN*sizeof(int), stream);
    k_count<<<E_GRID, 256, 0, stream>>>(dst, cnt);
    k_scanA<<<NB_SCAN, 512, 0, stream>>>(cnt, inc, bsum);
    k_scanB<<<1, 64, 0, stream>>>(bsum, boff);
    k_scanC<<<NB_SCAN, 512, 0, stream>>>(cnt, inc, boff, rowptr, cursor);
    k_fill<<<E_GRID, 256, 0, stream>>>(src, dst, cursor, eidx);

    for (int l = 0; l < LL; l++){
        // yb = relu(A' @ lin_W + b), A' = relu(bn(xb)) for l>0
        if (l == 0)
            k_gemm<0,1,0><<<GEMM_GRID, 256, 0, stream>>>(xb, WfLin + (size_t)l*16384, linB + (size_t)l*DD, nullptr, yb, nullptr, NN);
        else
            k_gemm<2,1,0><<<GEMM_GRID, 256, 0, stream>>>(xb, WfLin + (size_t)l*16384, linB + (size_t)l*DD, ss2, yb, nullptr, NN);
        // zb = A'*(1+eps) + gather(yb)
        k_agg<<<AGG_GRID, 256, 0, stream>>>(xb, yb, zb, rowptr, eidx, epsA, l, (l == 0) ? nullptr : ss2);
        // yb = zb @ mlp_W1 (+stats)
        hipMemsetAsync(stats, 0, 2*DD*sizeof(float), stream);
        k_gemm<0,0,1><<<GEMM_GRID, 256, 0, stream>>>(zb, WfW1 + (size_t)l*16384, nullptr, nullptr, yb, stats, NN);
        k_bnfin<<<1, 128, 0, stream>>>(stats, g1 + (size_t)l*DD, b1 + (size_t)l*DD, ss1);
        // xb = relu(bn(yb)) @ mlp_W2 (+stats)
        hipMemsetAsync(stats, 0, 2*DD*sizeof(float), stream);
        k_gemm<2,0,1><<<GEMM_GRID, 256, 0, stream>>>(yb, WfW2 + (size_t)l*16384, nullptr, ss1, xb, stats, NN);
        k_bnfin<<<1, 128, 0, stream>>>(stats, bng + (size_t)l*DD, bnb + (size_t)l*DD, ss2);
        // h_means[l] = mean_g relu(bn(xb))
        k_poolbn<<<GG, 128, 0, stream>>>(xb, ss2, goff, out_hmeans + (size_t)l*GG*DD, nullptr);
    }

    // pooling MLP
    hipMemsetAsync(stats, 0, 2*DD*sizeof(float), stream);
    k_gemm<2,0,1><<<GEMM_GRID, 256, 0, stream>>>(xb, WfPW1, nullptr, ss2, yb, stats, NN);
    k_bnfin<<<1, 128, 0, stream>>>(stats, pg1, pb1, ss1);
    hipMemsetAsync(stats, 0, 2*DD*sizeof(float), stream);
    k_gemm<2,0,1><<<GEMM_GRID, 256, 0, stream>>>(yb, WfPW2, nullptr, ss1, zb, stats, NN);
    k_bnfin<<<1, 128, 0, stream>>>(stats, pbng, pbnb, ss2);
    k_poolbn<<<GG, 128, 0, stream>>>(zb, ss2, goff, out_hgraph, hg);
    // predict
    k_pred1<<<GG, 256, 0, stream>>>(hg, prW1, prb1, ph);
    k_pred2<<<2, 256, 0, stream>>>(ph, prW2, prb2, out_pred);
}

// Round 10
// 623.710 us; speedup vs baseline: 4.8537x; 1.0819x over previous
//
#include <hip/hip_runtime.h>

typedef unsigned short ushort_t;
typedef __attribute__((ext_vector_type(8))) short bf16x8;
typedef __attribute__((ext_vector_type(4))) float f32x4;

#define NN 50000
#define NE 600000
#define DD 128
#define LL 3
#define GG 512
#define NB_SCAN 98   // ceil(NN/512)

__device__ __forceinline__ float b2f(ushort_t u){ return __uint_as_float(((unsigned)u)<<16); }
__device__ __forceinline__ ushort_t f2b(float f){
    unsigned x = __float_as_uint(f);
    return (ushort_t)((x + 0x7fffu + ((x>>16)&1u)) >> 16);
}

// ---- marker for host-side input-layout mismatch (f32 out) ----
__global__ void k_mark(float* __restrict__ out, float val, int n){
    int i = blockIdx.x*256 + threadIdx.x; if (i >= n) return;
    out[i] = (i == 0) ? val : 0.f;
}

// ---- weights: fp32 [k][n] -> bf16 in MFMA B-FRAGMENT order ----
// Wf[m][n][s][lane][i]: k = s*32 + (lane>>4)*8 + i, col = n*16 + (lane&15)
struct WPtrs { const float* p[11]; };
__global__ void k_wconv(WPtrs wp, ushort_t* __restrict__ Wf){
    int idx = blockIdx.x*256 + threadIdx.x;   // 11*16384
    if (idx >= 11*16384) return;
    int m = idx >> 14, r = idx & 16383;
    int i = r & 7, l = (r >> 3) & 63, s = (r >> 9) & 3, n = r >> 11;
    int k   = s*32 + (l >> 4)*8 + i;
    int col = n*16 + (l & 15);
    Wf[idx] = f2b(wp.p[m][k*DD + col]);
}

// ---------------- embed -> bf16 ----------------
__global__ void k_embed(const int* __restrict__ d, const float* __restrict__ tab,
                        ushort_t* __restrict__ xb){
    int idx = blockIdx.x*256 + threadIdx.x;
    if (idx >= NN*DD) return;
    int row = idx >> 7, c = idx & 127;
    int di = d[row]; di = di < 0 ? 0 : (di > 5 ? 5 : di);
    xb[idx] = f2b(tab[di*DD + c]);
}

// ---------------- group offsets ----------------
__global__ void k_goff(const int* __restrict__ bids, int* __restrict__ goff){
    int g = blockIdx.x*256 + threadIdx.x;
    if (g > GG) return;
    int lo = 0, hi = NN;
    while (lo < hi){ int mid = (lo+hi) >> 1; if (bids[mid] < g) lo = mid+1; else hi = mid; }
    goff[g] = lo;
}

// ---------------- CSR build ----------------
__global__ void k_count(const int* __restrict__ dst, int* __restrict__ cnt){
    int e = blockIdx.x*256 + threadIdx.x; if (e >= NE) return;
    atomicAdd(&cnt[dst[e]], 1);
}
__global__ void k_scanA(const int* __restrict__ cnt, int* __restrict__ inc, int* __restrict__ bsum){
    __shared__ int s[512];
    int i = blockIdx.x*512 + threadIdx.x;
    int v = (i < NN) ? cnt[i] : 0;
    s[threadIdx.x] = v; __syncthreads();
    for (int off = 1; off < 512; off <<= 1){
        int add = (threadIdx.x >= off) ? s[threadIdx.x - off] : 0;
        __syncthreads();
        s[threadIdx.x] += add;
        __syncthreads();
    }
    if (i < NN) inc[i] = s[threadIdx.x];
    if (threadIdx.x == 511) bsum[blockIdx.x] = s[511];
}
__global__ void k_scanB(const int* __restrict__ bsum, int* __restrict__ boff){
    if (threadIdx.x == 0 && blockIdx.x == 0){
        int acc = 0;
        for (int b = 0; b < NB_SCAN; b++){ boff[b] = acc; acc += bsum[b]; }
        boff[NB_SCAN] = acc;
    }
}
__global__ void k_scanC(const int* __restrict__ cnt, const int* __restrict__ inc,
                        const int* __restrict__ boff, int* __restrict__ rowptr,
                        int* __restrict__ cursor){
    int i = blockIdx.x*512 + threadIdx.x;
    if (i < NN){
        int e = boff[blockIdx.x] + inc[i] - cnt[i];
        rowptr[i] = e; cursor[i] = e;
    } else if (i == NN){
        rowptr[NN] = NE;
    }
}
__global__ void k_fill(const int* __restrict__ src, const int* __restrict__ dst,
                       int* __restrict__ cursor, int* __restrict__ eidx){
    int e = blockIdx.x*256 + threadIdx.x; if (e >= NE) return;
    int p = atomicAdd(&cursor[dst[e]], 1);
    eidx[p] = src[e];
}

// ---- aggregation: 16 lanes/node, edge loop unrolled x4, BN-from-stats inline ----
template<int USE_SS>
__global__ void k_agg(const ushort_t* __restrict__ xb, const ushort_t* __restrict__ yb,
                      ushort_t* __restrict__ zb,
                      const int* __restrict__ rowptr, const int* __restrict__ eidx,
                      const float* __restrict__ epsP, int l,
                      const float* __restrict__ bnstats, const float* __restrict__ bng,
                      const float* __restrict__ bnb){
    int node = blockIdx.x*16 + (threadIdx.x >> 4);
    if (node >= NN) return;
    int c8 = (threadIdx.x & 15) << 3;
    float epl = 1.0f + epsP[l];
    bf16x8 xr = *(const bf16x8*)(xb + (size_t)node*DD + c8);
    float a[8];
#pragma unroll
    for (int i = 0; i < 8; i++) a[i] = b2f((ushort_t)xr[i]);
    if (USE_SS){
#pragma unroll
        for (int i = 0; i < 8; i++){
            int c = c8 + i;
            float mu  = bnstats[c] * (1.0f/NN);
            float var = bnstats[c + DD] * (1.0f/NN) - mu*mu;
            float sc  = rsqrtf(fmaxf(var, 0.f) + 1e-5f) * bng[c];
            float sh  = bnb[c] - mu*sc;
            a[i] = fmaxf(fmaf(a[i], sc, sh), 0.f);
        }
    }
#pragma unroll
    for (int i = 0; i < 8; i++) a[i] *= epl;
    int e0 = rowptr[node], e1 = rowptr[node+1];
    int e = e0;
    for (; e + 3 < e1; e += 4){
        int s0 = eidx[e], s1 = eidx[e+1], s2 = eidx[e+2], s3 = eidx[e+3];
        bf16x8 v0 = *(const bf16x8*)(yb + (size_t)s0*DD + c8);
        bf16x8 v1 = *(const bf16x8*)(yb + (size_t)s1*DD + c8);
        bf16x8 v2 = *(const bf16x8*)(yb + (size_t)s2*DD + c8);
        bf16x8 v3 = *(const bf16x8*)(yb + (size_t)s3*DD + c8);
#pragma unroll
        for (int i = 0; i < 8; i++)
            a[i] += (b2f((ushort_t)v0[i]) + b2f((ushort_t)v1[i]))
                  + (b2f((ushort_t)v2[i]) + b2f((ushort_t)v3[i]));
    }
    for (; e < e1; e++){
        int s = eidx[e];
        bf16x8 v = *(const bf16x8*)(yb + (size_t)s*DD + c8);
#pragma unroll
        for (int i = 0; i < 8; i++) a[i] += b2f((ushort_t)v[i]);
    }
    bf16x8 o;
#pragma unroll
    for (int i = 0; i < 8; i++) o[i] = (short)f2b(a[i]);
    *(bf16x8*)(zb + (size_t)node*DD + c8) = o;
}

// ---------------- MFMA GEMM: C[M,128] = op(A') @ W  (bf16, fp32 accum) ----
// AMODE 2: A' = relu(bn(A)) with scale/shift computed in-block from raw stats.
// STATS 1: column sum/sumsq of C atomically into stats_out[256].
template<int AMODE, int OMODE, int STATS>
__global__ __launch_bounds__(256) void k_gemm(
    const ushort_t* __restrict__ A, const ushort_t* __restrict__ Wf,
    const float* __restrict__ bias,
    const float* __restrict__ bnstats, const float* __restrict__ bng,
    const float* __restrict__ bnb,
    ushort_t* __restrict__ C, float* __restrict__ stats_out, int M)
{
    __shared__ float ssl[256];
    __shared__ float sred[256];
    const int t = threadIdx.x;
    const int w = t >> 6;                    // wave 0..3
    const int l = t & 63;
    const int rowBase = blockIdx.x * 64 + w * 16;
    const int lm = l & 15;
    const int kg = l >> 4;

    if (AMODE == 2 && t < 128){
        float mu  = bnstats[t] * (1.0f/NN);
        float var = bnstats[t + DD] * (1.0f/NN) - mu*mu;
        float sc  = rsqrtf(fmaxf(var, 0.f) + 1e-5f) * bng[t];
        ssl[t] = sc;
        ssl[t + DD] = bnb[t] - mu*sc;
    }
    if (STATS) sred[t] = 0.f;
    if (AMODE == 2 || STATS) __syncthreads();

    f32x4 acc[8];
#pragma unroll
    for (int n = 0; n < 8; n++) acc[n] = (f32x4){0.f,0.f,0.f,0.f};

    int arow = rowBase + lm;
    if (arow >= M) arow = M - 1;             // clamp; pad rows masked at store/stats
    const ushort_t* aptr = A + (size_t)arow*DD + kg*8;

#pragma unroll
    for (int s = 0; s < 4; s++){
        bf16x8 af;
        if (AMODE == 0){
            af = *(const bf16x8*)(aptr + s*32);
        } else {
            bf16x8 ar = *(const bf16x8*)(aptr + s*32);
            int k0 = s*32 + kg*8;
#pragma unroll
            for (int i = 0; i < 8; i++){
                float v = b2f((ushort_t)ar[i]);
                v = fmaxf(fmaf(v, ssl[k0+i], ssl[DD+k0+i]), 0.f);
                ((ushort_t*)&af)[i] = f2b(v);
            }
        }
#pragma unroll
        for (int n = 0; n < 8; n++){
            bf16x8 bfr = *(const bf16x8*)(Wf + (size_t)((n*4 + s)*64 + l)*8);
            acc[n] = __builtin_amdgcn_mfma_f32_16x16x32_bf16(af, bfr, acc[n], 0, 0, 0);
        }
    }

    // D layout: tile n -> col = n*16 + lm, rows rowBase + kg*4 + j
#pragma unroll
    for (int n = 0; n < 8; n++){
        int col = n*16 + lm;
        float cs = 0.f, cq = 0.f;
#pragma unroll
        for (int j = 0; j < 4; j++){
            int row = rowBase + kg*4 + j;
            float v = acc[n][j];
            if (OMODE == 1) v = fmaxf(v + bias[col], 0.f);
            if (row < M){
                C[(size_t)row*DD + col] = f2b(v);
                if (STATS){ cs += v; cq += v*v; }
            }
        }
        if (STATS){
            cs += __shfl_xor(cs, 16); cs += __shfl_xor(cs, 32);
            cq += __shfl_xor(cq, 16); cq += __shfl_xor(cq, 32);
            if (kg == 0){
                atomicAdd(&sred[col], cs);
                atomicAdd(&sred[col + DD], cq);
            }
        }
    }
    if (STATS){
        __syncthreads();
        atomicAdd(&stats_out[t], sred[t]);
    }
}

// ---------------- pooling with inline BN+ReLU (bf16 in, f32 out) ----------------
__global__ void k_poolbn(const ushort_t* __restrict__ h,
                         const float* __restrict__ bnstats, const float* __restrict__ bng,
                         const float* __restrict__ bnb,
                         const int* __restrict__ goff, float* __restrict__ outp,
                         float* __restrict__ outf){
    int g = blockIdx.x;
    int c = threadIdx.x;           // 128 threads
    float mu  = bnstats[c] * (1.0f/NN);
    float var = bnstats[c + DD] * (1.0f/NN) - mu*mu;
    float sc  = rsqrtf(fmaxf(var, 0.f) + 1e-5f) * bng[c];
    float sh  = bnb[c] - mu*sc;
    int r0 = goff[g], r1 = goff[g+1];
    float acc = 0.f;
    for (int r = r0; r < r1; r++)
        acc += fmaxf(fmaf(b2f(h[(size_t)r*DD + c]), sc, sh), 0.f);
    float m = acc / fmaxf((float)(r1 - r0), 1.0f);
    outp[g*DD + c] = m;
    if (outf) outf[g*DD + c] = m;
}

// ---------------- predict head (fp32) ----------------
__global__ void k_pred1(const float* __restrict__ hg, const float* __restrict__ W1,
                        const float* __restrict__ b1, float* __restrict__ ph){
    int idx = blockIdx.x*256 + threadIdx.x;
    if (idx >= GG*256) return;
    int g = idx >> 8, j = idx & 255;
    float acc = b1[j];
    for (int k = 0; k < DD; k++) acc = fmaf(hg[g*DD + k], W1[k*256 + j], acc);
    ph[idx] = fmaxf(acc, 0.f);
}
__global__ void k_pred2(const float* __restrict__ ph, const float* __restrict__ W2,
                        const float* __restrict__ b2, float* __restrict__ out){
    int g = blockIdx.x*256 + threadIdx.x; if (g >= GG) return;
    float acc = b2[0];
    for (int k = 0; k < 256; k++) acc = fmaf(ph[g*256 + k], W2[k], acc);
    out[g] = acc;
}

extern "C" void kernel_launch(void* const* d_in, const int* in_sizes, int n_in,
                              void* d_out, int out_size, void* d_ws, size_t ws_size,
                              hipStream_t stream){
    float* out = (float*)d_out;
    const int OUT_N = GG + GG*DD + LL*GG*DD;      // 262656

    static const int EXP[24] = {50000,600000,600000,50000, 768,49152,384,49152,384,384,
                                49152,3,384,384,16384,128,128,16384,128,128,
                                32768,256,256,1};
    int bad = -1;
    if (n_in != 24) bad = 50;
    else for (int i = 0; i < 24; i++) if (in_sizes[i] != EXP[i]) { bad = i; break; }
    if (bad >= 0){
        k_mark<<<(OUT_N+255)/256, 256, 0, stream>>>(out, 2048.0f + (float)bad, OUT_N);
        return;
    }

    const int* d    = (const int*)d_in[0];
    const int* src  = (const int*)d_in[1];
    const int* dst  = (const int*)d_in[2];
    const int* bids = (const int*)d_in[3];
    const float* emb  = (const float*)d_in[4];
    const float* linW = (const float*)d_in[5];
    const float* linB = (const float*)d_in[6];
    const float* W1   = (const float*)d_in[7];
    const float* g1   = (const float*)d_in[8];
    const float* b1   = (const float*)d_in[9];
    const float* W2   = (const float*)d_in[10];
    const float* epsA = (const float*)d_in[11];
    const float* bng  = (const float*)d_in[12];
    const float* bnb  = (const float*)d_in[13];
    const float* pW1  = (const float*)d_in[14];
    const float* pg1  = (const float*)d_in[15];
    const float* pb1  = (const float*)d_in[16];
    const float* pW2  = (const float*)d_in[17];
    const float* pbng = (const float*)d_in[18];
    const float* pbnb = (const float*)d_in[19];
    const float* prW1 = (const float*)d_in[20];
    const float* prb1 = (const float*)d_in[21];
    const float* prW2 = (const float*)d_in[22];
    const float* prb2 = (const float*)d_in[23];

    // ---- workspace (~45 MB) ----
    ushort_t* xb  = (ushort_t*)d_ws;              // NN*DD bf16
    ushort_t* yb  = xb + (size_t)NN*DD;
    ushort_t* zb  = yb + (size_t)NN*DD;
    ushort_t* Wf  = zb + (size_t)NN*DD;           // 11*16384 bf16
    float* SR    = (float*)(Wf + 11*16384);       // 8*256 stats regions
    float* hg    = SR + 8*256;                    // GG*DD
    float* ph    = hg + (size_t)GG*DD;            // GG*256
    int* cnt    = (int*)(ph + (size_t)GG*256);
    int* inc    = cnt + NN;
    int* rowptr = inc + NN;                       // N+1
    int* cursor = rowptr + NN + 1;
    int* eidx   = cursor + NN;                    // E
    int* goff   = eidx + NE;                      // G+1
    int* bsum   = goff + GG + 1;
    int* boff   = bsum + NB_SCAN;

    float* out_pred   = out;
    float* out_hgraph = out + GG;
    float* out_hmeans = out + GG + GG*DD;

    const int NW_GRID  = (NN*DD + 255)/256;       // 25000
    const int E_GRID   = (NE + 255)/256;          // 2344
    const int AGG_GRID = (NN + 15)/16;            // 3125
    const int GEMM_GRID= (NN + 63)/64;            // 782

    // weight convert -> fragment order
    WPtrs wp;
    for (int i = 0; i < 3; i++){
        wp.p[i]   = linW + (size_t)i*DD*DD;
        wp.p[3+i] = W1   + (size_t)i*DD*DD;
        wp.p[6+i] = W2   + (size_t)i*DD*DD;
    }
    wp.p[9] = pW1; wp.p[10] = pW2;
    k_wconv<<<(11*16384 + 255)/256, 256, 0, stream>>>(wp, Wf);
    const ushort_t* WfLin = Wf;
    const ushort_t* WfW1  = Wf + 3*16384;
    const ushort_t* WfW2  = Wf + 6*16384;
    const ushort_t* WfPW1 = Wf + 9*16384;
    const ushort_t* WfPW2 = Wf + 10*16384;

    // zero all stats regions once + CSR counters
    hipMemsetAsync(SR, 0, 8*256*sizeof(float), stream);
    hipMemsetAsync(cnt, 0, NN*sizeof(int), stream);

    // node features + graph boundaries + CSR (once)
    k_embed<<<NW_GRID, 256, 0, stream>>>(d, emb, xb);
    k_goff<<<3, 256, 0, stream>>>(bids, goff);
    k_count<<<E_GRID, 256, 0, stream>>>(dst, cnt);
    k_scanA<<<NB_SCAN, 512, 0, stream>>>(cnt, inc, bsum);
    k_scanB<<<1, 64, 0, stream>>>(bsum, boff);
    k_scanC<<<NB_SCAN, 512, 0, stream>>>(cnt, inc, boff, rowptr, cursor);
    k_fill<<<E_GRID, 256, 0, stream>>>(src, dst, cursor, eidx);

    for (int l = 0; l < LL; l++){
        const float* pstat = SR + (2*l - 1)*256;          // outer BN of prev layer (l>0)
        const float* pg    = bng + (size_t)(l-1)*DD;
        const float* pb    = bnb + (size_t)(l-1)*DD;
        float* statsIn  = SR + (2*l)*256;                 // inner BN of this layer
        float* statsOut = SR + (2*l + 1)*256;             // outer BN of this layer

        // yb = relu(A' @ lin_W + b), A' = relu(bn(xb)) for l>0
        if (l == 0)
            k_gemm<0,1,0><<<GEMM_GRID, 256, 0, stream>>>(xb, WfLin, linB, nullptr, nullptr, nullptr, yb, nullptr, NN);
        else
            k_gemm<2,1,0><<<GEMM_GRID, 256, 0, stream>>>(xb, WfLin + (size_t)l*16384, linB + (size_t)l*DD, pstat, pg, pb, yb, nullptr, NN);
        // zb = A'*(1+eps) + gather(yb)
        if (l == 0)
            k_agg<0><<<AGG_GRID, 256, 0, stream>>>(xb, yb, zb, rowptr, eidx, epsA, l, nullptr, nullptr, nullptr);
        else
            k_agg<1><<<AGG_GRID, 256, 0, stream>>>(xb, yb, zb, rowptr, eidx, epsA, l, pstat, pg, pb);
        // yb = zb @ mlp_W1 (+stats)
        k_gemm<0,0,1><<<GEMM_GRID, 256, 0, stream>>>(zb, WfW1 + (size_t)l*16384, nullptr, nullptr, nullptr, nullptr, yb, statsIn, NN);
        // xb = relu(bn(yb)) @ mlp_W2 (+stats)
        k_gemm<2,0,1><<<GEMM_GRID, 256, 0, stream>>>(yb, WfW2 + (size_t)l*16384, nullptr, statsIn, g1 + (size_t)l*DD, b1 + (size_t)l*DD, xb, statsOut, NN);
        // h_means[l] = mean_g relu(bn(xb))
        k_poolbn<<<GG, 128, 0, stream>>>(xb, statsOut, bng + (size_t)l*DD, bnb + (size_t)l*DD, goff, out_hmeans + (size_t)l*GG*DD, nullptr);
    }

    // pooling MLP
    k_gemm<2,0,1><<<GEMM_GRID, 256, 0, stream>>>(xb, WfPW1, nullptr, SR + 5*256, bng + 2*DD, bnb + 2*DD, yb, SR + 6*256, NN);
    k_gemm<2,0,1><<<GEMM_GRID, 256, 0, stream>>>(yb, WfPW2, nullptr, SR + 6*256, pg1, pb1, zb, SR + 7*256, NN);
    k_poolbn<<<GG, 128, 0, stream>>>(zb, SR + 7*256, pbng, pbnb, goff, out_hgraph, hg);
    // predict
    k_pred1<<<GG, 256, 0, stream>>>(hg, prW1, prb1, ph);
    k_pred2<<<2, 256, 0, stream>>>(ph, prW2, prb2, out_pred);
}

// Round 11
// 587.805 us; speedup vs baseline: 5.1502x; 1.0611x over previous
//
#include <hip/hip_runtime.h>

typedef unsigned short ushort_t;
typedef __attribute__((ext_vector_type(8))) short bf16x8;
typedef __attribute__((ext_vector_type(4))) float f32x4;

#define NN 50000
#define NE 600000
#define DD 128
#define LL 3
#define GG 512
#define NB_SCAN 98   // ceil(NN/512)

__device__ __forceinline__ float b2f(ushort_t u){ return __uint_as_float(((unsigned)u)<<16); }
__device__ __forceinline__ ushort_t f2b(float f){
    unsigned x = __float_as_uint(f);
    return (ushort_t)((x + 0x7fffu + ((x>>16)&1u)) >> 16);
}

// ---- marker for host-side input-layout mismatch (f32 out) ----
__global__ void k_mark(float* __restrict__ out, float val, int n){
    int i = blockIdx.x*256 + threadIdx.x; if (i >= n) return;
    out[i] = (i == 0) ? val : 0.f;
}

// ---- weights: fp32 [k][n] -> bf16 in MFMA B-FRAGMENT order ----
struct WPtrs { const float* p[11]; };
__global__ void k_wconv(WPtrs wp, ushort_t* __restrict__ Wf){
    int idx = blockIdx.x*256 + threadIdx.x;   // 11*16384
    if (idx >= 11*16384) return;
    int m = idx >> 14, r = idx & 16383;
    int i = r & 7, l = (r >> 3) & 63, s = (r >> 9) & 3, n = r >> 11;
    int k   = s*32 + (l >> 4)*8 + i;
    int col = n*16 + (l & 15);
    Wf[idx] = f2b(wp.p[m][k*DD + col]);
}

// ---------------- group offsets ----------------
__global__ void k_goff(const int* __restrict__ bids, int* __restrict__ goff){
    int g = blockIdx.x*256 + threadIdx.x;
    if (g > GG) return;
    int lo = 0, hi = NN;
    while (lo < hi){ int mid = (lo+hi) >> 1; if (bids[mid] < g) lo = mid+1; else hi = mid; }
    goff[g] = lo;
}

// ---------------- CSR build ----------------
__global__ void k_count(const int* __restrict__ dst, int* __restrict__ cnt){
    int e = blockIdx.x*256 + threadIdx.x; if (e >= NE) return;
    atomicAdd(&cnt[dst[e]], 1);
}
__global__ void k_scanA(const int* __restrict__ cnt, int* __restrict__ inc, int* __restrict__ bsum){
    __shared__ int s[512];
    int i = blockIdx.x*512 + threadIdx.x;
    int v = (i < NN) ? cnt[i] : 0;
    s[threadIdx.x] = v; __syncthreads();
    for (int off = 1; off < 512; off <<= 1){
        int add = (threadIdx.x >= off) ? s[threadIdx.x - off] : 0;
        __syncthreads();
        s[threadIdx.x] += add;
        __syncthreads();
    }
    if (i < NN) inc[i] = s[threadIdx.x];
    if (threadIdx.x == 511) bsum[blockIdx.x] = s[511];
}
__global__ void k_scanB(const int* __restrict__ bsum, int* __restrict__ boff){
    if (threadIdx.x == 0 && blockIdx.x == 0){
        int acc = 0;
        for (int b = 0; b < NB_SCAN; b++){ boff[b] = acc; acc += bsum[b]; }
        boff[NB_SCAN] = acc;
    }
}
__global__ void k_scanC(const int* __restrict__ cnt, const int* __restrict__ inc,
                        const int* __restrict__ boff, int* __restrict__ rowptr,
                        int* __restrict__ cursor){
    int i = blockIdx.x*512 + threadIdx.x;
    if (i < NN){
        int e = boff[blockIdx.x] + inc[i] - cnt[i];
        rowptr[i] = e; cursor[i] = e;
    } else if (i == NN){
        rowptr[NN] = NE;
    }
}
__global__ void k_fill(const int* __restrict__ src, const int* __restrict__ dst,
                       int* __restrict__ cursor, int* __restrict__ eidx){
    int e = blockIdx.x*256 + threadIdx.x; if (e >= NE) return;
    int p = atomicAdd(&cursor[dst[e]], 1);
    eidx[p] = src[e];
}

// ---- layer-0 message table: yrows[di][c] = relu(emb[di]@linW + linB), 6x128 ----
__global__ void k_lin0(const float* __restrict__ emb, const float* __restrict__ linW,
                       const float* __restrict__ linB, float* __restrict__ yrows){
    int di = blockIdx.x;          // 6
    int c  = threadIdx.x;         // 128
    float acc = linB[c];
    for (int k = 0; k < DD; k++) acc = fmaf(emb[di*DD + k], linW[k*DD + c], acc);
    yrows[di*DD + c] = fmaxf(acc, 0.f);
}

// ---- layer-0 aggregation from 6-row LUTs (all LDS): ----
// zb[v] = emb[d[v]]*(1+eps0) + sum_{e: dst=v} yrows[d[src_e]]
__global__ void k_agg0(const int* __restrict__ d, const float* __restrict__ emb,
                       const float* __restrict__ yrows,
                       const int* __restrict__ rowptr, const int* __restrict__ eidx,
                       const float* __restrict__ epsP, ushort_t* __restrict__ zb){
    __shared__ float eL[6*DD], yL[6*DD];
    int t = threadIdx.x;
    for (int i = t; i < 6*DD; i += 256){ eL[i] = emb[i]; yL[i] = yrows[i]; }
    __syncthreads();
    int node = blockIdx.x*16 + (t >> 4);
    if (node >= NN) return;
    int c8 = (t & 15) << 3;
    float epl = 1.0f + epsP[0];
    int dv = d[node]; dv = dv < 0 ? 0 : (dv > 5 ? 5 : dv);
    float a[8];
#pragma unroll
    for (int i = 0; i < 8; i++) a[i] = eL[dv*DD + c8 + i] * epl;
    int e0 = rowptr[node], e1 = rowptr[node+1];
    int e = e0;
    for (; e + 3 < e1; e += 4){
        int s0 = eidx[e], s1 = eidx[e+1], s2 = eidx[e+2], s3 = eidx[e+3];
        int c0 = d[s0], c1 = d[s1], c2 = d[s2], c3 = d[s3];
        c0 = c0 < 0 ? 0 : (c0 > 5 ? 5 : c0);
        c1 = c1 < 0 ? 0 : (c1 > 5 ? 5 : c1);
        c2 = c2 < 0 ? 0 : (c2 > 5 ? 5 : c2);
        c3 = c3 < 0 ? 0 : (c3 > 5 ? 5 : c3);
#pragma unroll
        for (int i = 0; i < 8; i++)
            a[i] += (yL[c0*DD + c8 + i] + yL[c1*DD + c8 + i])
                  + (yL[c2*DD + c8 + i] + yL[c3*DD + c8 + i]);
    }
    for (; e < e1; e++){
        int s = eidx[e];
        int c = d[s]; c = c < 0 ? 0 : (c > 5 ? 5 : c);
#pragma unroll
        for (int i = 0; i < 8; i++) a[i] += yL[c*DD + c8 + i];
    }
    bf16x8 o;
#pragma unroll
    for (int i = 0; i < 8; i++) o[i] = (short)f2b(a[i]);
    *(bf16x8*)(zb + (size_t)node*DD + c8) = o;
}

// ---- aggregation layers>0: 16 lanes/node, unroll x4, BN-from-stats inline ----
__global__ void k_agg(const ushort_t* __restrict__ xb, const ushort_t* __restrict__ yb,
                      ushort_t* __restrict__ zb,
                      const int* __restrict__ rowptr, const int* __restrict__ eidx,
                      const float* __restrict__ epsP, int l,
                      const float* __restrict__ bnstats, const float* __restrict__ bng,
                      const float* __restrict__ bnb){
    int node = blockIdx.x*16 + (threadIdx.x >> 4);
    if (node >= NN) return;
    int c8 = (threadIdx.x & 15) << 3;
    float epl = 1.0f + epsP[l];
    bf16x8 xr = *(const bf16x8*)(xb + (size_t)node*DD + c8);
    float a[8];
#pragma unroll
    for (int i = 0; i < 8; i++){
        int c = c8 + i;
        float mu  = bnstats[c] * (1.0f/NN);
        float var = bnstats[c + DD] * (1.0f/NN) - mu*mu;
        float sc  = rsqrtf(fmaxf(var, 0.f) + 1e-5f) * bng[c];
        float sh  = bnb[c] - mu*sc;
        a[i] = fmaxf(fmaf(b2f((ushort_t)xr[i]), sc, sh), 0.f) * epl;
    }
    int e0 = rowptr[node], e1 = rowptr[node+1];
    int e = e0;
    for (; e + 3 < e1; e += 4){
        int s0 = eidx[e], s1 = eidx[e+1], s2 = eidx[e+2], s3 = eidx[e+3];
        bf16x8 v0 = *(const bf16x8*)(yb + (size_t)s0*DD + c8);
        bf16x8 v1 = *(const bf16x8*)(yb + (size_t)s1*DD + c8);
        bf16x8 v2 = *(const bf16x8*)(yb + (size_t)s2*DD + c8);
        bf16x8 v3 = *(const bf16x8*)(yb + (size_t)s3*DD + c8);
#pragma unroll
        for (int i = 0; i < 8; i++)
            a[i] += (b2f((ushort_t)v0[i]) + b2f((ushort_t)v1[i]))
                  + (b2f((ushort_t)v2[i]) + b2f((ushort_t)v3[i]));
    }
    for (; e < e1; e++){
        int s = eidx[e];
        bf16x8 v = *(const bf16x8*)(yb + (size_t)s*DD + c8);
#pragma unroll
        for (int i = 0; i < 8; i++) a[i] += b2f((ushort_t)v[i]);
    }
    bf16x8 o;
#pragma unroll
    for (int i = 0; i < 8; i++) o[i] = (short)f2b(a[i]);
    *(bf16x8*)(zb + (size_t)node*DD + c8) = o;
}

// ---------------- MFMA GEMM with LDS-repacked coalesced epilogue ----------------
// AMODE 2: A' = relu(bn(A)) with scale/shift computed in-block from raw stats.
// OMODE 1: relu(C + bias). STATS 1: column sum/sumsq of C atomically into stats_out.
template<int AMODE, int OMODE, int STATS>
__global__ __launch_bounds__(256) void k_gemm(
    const ushort_t* __restrict__ A, const ushort_t* __restrict__ Wf,
    const float* __restrict__ bias,
    const float* __restrict__ bnstats, const float* __restrict__ bng,
    const float* __restrict__ bnb,
    ushort_t* __restrict__ C, float* __restrict__ stats_out, int M)
{
    __shared__ float ssl[256];
    __shared__ float sred[256];
    __shared__ float lrep[64*132];           // f32 [64][132] repack (pad 132)
    const int t = threadIdx.x;
    const int w = t >> 6;                    // wave 0..3
    const int l = t & 63;
    const int rowBlk  = blockIdx.x * 64;
    const int rowBase = rowBlk + w * 16;
    const int lm = l & 15;
    const int kg = l >> 4;

    if (AMODE == 2 && t < 128){
        float mu  = bnstats[t] * (1.0f/NN);
        float var = bnstats[t + DD] * (1.0f/NN) - mu*mu;
        float sc  = rsqrtf(fmaxf(var, 0.f) + 1e-5f) * bng[t];
        ssl[t] = sc;
        ssl[t + DD] = bnb[t] - mu*sc;
    }
    if (STATS) sred[t] = 0.f;
    if (AMODE == 2 || STATS) __syncthreads();

    f32x4 acc[8];
#pragma unroll
    for (int n = 0; n < 8; n++) acc[n] = (f32x4){0.f,0.f,0.f,0.f};

    int arow = rowBase + lm;
    if (arow >= M) arow = M - 1;             // clamp; pad rows masked later
    const ushort_t* aptr = A + (size_t)arow*DD + kg*8;

#pragma unroll
    for (int s = 0; s < 4; s++){
        bf16x8 af;
        if (AMODE == 0){
            af = *(const bf16x8*)(aptr + s*32);
        } else {
            bf16x8 ar = *(const bf16x8*)(aptr + s*32);
            int k0 = s*32 + kg*8;
#pragma unroll
            for (int i = 0; i < 8; i++){
                float v = b2f((ushort_t)ar[i]);
                v = fmaxf(fmaf(v, ssl[k0+i], ssl[DD+k0+i]), 0.f);
                ((ushort_t*)&af)[i] = f2b(v);
            }
        }
#pragma unroll
        for (int n = 0; n < 8; n++){
            bf16x8 bfr = *(const bf16x8*)(Wf + (size_t)((n*4 + s)*64 + l)*8);
            acc[n] = __builtin_amdgcn_mfma_f32_16x16x32_bf16(af, bfr, acc[n], 0, 0, 0);
        }
    }

    // transform + stats + LDS repack (D: col=n*16+lm, local row = w*16+kg*4+j)
#pragma unroll
    for (int n = 0; n < 8; n++){
        int col = n*16 + lm;
        float cs = 0.f, cq = 0.f;
#pragma unroll
        for (int j = 0; j < 4; j++){
            float v = acc[n][j];
            if (OMODE == 1) v = fmaxf(v + bias[col], 0.f);
            lrep[(w*16 + kg*4 + j)*132 + col] = v;
            if (STATS && (rowBase + kg*4 + j) < M){ cs += v; cq += v*v; }
        }
        if (STATS){
            cs += __shfl_xor(cs, 16); cs += __shfl_xor(cs, 32);
            cq += __shfl_xor(cq, 16); cq += __shfl_xor(cq, 32);
            if (kg == 0){
                atomicAdd(&sred[col], cs);
                atomicAdd(&sred[col + DD], cq);
            }
        }
    }
    __syncthreads();

    // coalesced store: thread t -> local row t&63, 32-col segment (t>>6)
    {
        int lr  = t & 63;
        int gr  = rowBlk + lr;
        if (gr < M){
            int seg = (t >> 6) * 32;
            const float* lp = lrep + lr*132 + seg;
            bf16x8 o0, o1, o2, o3;
#pragma unroll
            for (int i = 0; i < 8; i++){
                o0[i] = (short)f2b(lp[i]);
                o1[i] = (short)f2b(lp[8+i]);
                o2[i] = (short)f2b(lp[16+i]);
                o3[i] = (short)f2b(lp[24+i]);
            }
            ushort_t* cp = C + (size_t)gr*DD + seg;
            *(bf16x8*)(cp)      = o0;
            *(bf16x8*)(cp + 8)  = o1;
            *(bf16x8*)(cp + 16) = o2;
            *(bf16x8*)(cp + 24) = o3;
        }
    }

    if (STATS){
        __syncthreads();
        atomicAdd(&stats_out[t], sred[t]);
    }
}

// ---------------- pooling with inline BN+ReLU (bf16 in, f32 out) ----------------
__global__ void k_poolbn(const ushort_t* __restrict__ h,
                         const float* __restrict__ bnstats, const float* __restrict__ bng,
                         const float* __restrict__ bnb,
                         const int* __restrict__ goff, float* __restrict__ outp,
                         float* __restrict__ outf){
    int g = blockIdx.x;
    int c = threadIdx.x;           // 128 threads
    float mu  = bnstats[c] * (1.0f/NN);
    float var = bnstats[c + DD] * (1.0f/NN) - mu*mu;
    float sc  = rsqrtf(fmaxf(var, 0.f) + 1e-5f) * bng[c];
    float sh  = bnb[c] - mu*sc;
    int r0 = goff[g], r1 = goff[g+1];
    float acc = 0.f;
    for (int r = r0; r < r1; r++)
        acc += fmaxf(fmaf(b2f(h[(size_t)r*DD + c]), sc, sh), 0.f);
    float m = acc / fmaxf((float)(r1 - r0), 1.0f);
    outp[g*DD + c] = m;
    if (outf) outf[g*DD + c] = m;
}

// ---------------- predict head (fp32) ----------------
__global__ void k_pred1(const float* __restrict__ hg, const float* __restrict__ W1,
                        const float* __restrict__ b1, float* __restrict__ ph){
    int idx = blockIdx.x*256 + threadIdx.x;
    if (idx >= GG*256) return;
    int g = idx >> 8, j = idx & 255;
    float acc = b1[j];
    for (int k = 0; k < DD; k++) acc = fmaf(hg[g*DD + k], W1[k*256 + j], acc);
    ph[idx] = fmaxf(acc, 0.f);
}
__global__ void k_pred2(const float* __restrict__ ph, const float* __restrict__ W2,
                        const float* __restrict__ b2, float* __restrict__ out){
    int g = blockIdx.x*256 + threadIdx.x; if (g >= GG) return;
    float acc = b2[0];
    for (int k = 0; k < 256; k++) acc = fmaf(ph[g*256 + k], W2[k], acc);
    out[g] = acc;
}

extern "C" void kernel_launch(void* const* d_in, const int* in_sizes, int n_in,
                              void* d_out, int out_size, void* d_ws, size_t ws_size,
                              hipStream_t stream){
    float* out = (float*)d_out;
    const int OUT_N = GG + GG*DD + LL*GG*DD;      // 262656

    static const int EXP[24] = {50000,600000,600000,50000, 768,49152,384,49152,384,384,
                                49152,3,384,384,16384,128,128,16384,128,128,
                                32768,256,256,1};
    int bad = -1;
    if (n_in != 24) bad = 50;
    else for (int i = 0; i < 24; i++) if (in_sizes[i] != EXP[i]) { bad = i; break; }
    if (bad >= 0){
        k_mark<<<(OUT_N+255)/256, 256, 0, stream>>>(out, 2048.0f + (float)bad, OUT_N);
        return;
    }

    const int* d    = (const int*)d_in[0];
    const int* src  = (const int*)d_in[1];
    const int* dst  = (const int*)d_in[2];
    const int* bids = (const int*)d_in[3];
    const float* emb  = (const float*)d_in[4];
    const float* linW = (const float*)d_in[5];
    const float* linB = (const float*)d_in[6];
    const float* W1   = (const float*)d_in[7];
    const float* g1   = (const float*)d_in[8];
    const float* b1   = (const float*)d_in[9];
    const float* W2   = (const float*)d_in[10];
    const float* epsA = (const float*)d_in[11];
    const float* bng  = (const float*)d_in[12];
    const float* bnb  = (const float*)d_in[13];
    const float* pW1  = (const float*)d_in[14];
    const float* pg1  = (const float*)d_in[15];
    const float* pb1  = (const float*)d_in[16];
    const float* pW2  = (const float*)d_in[17];
    const float* pbng = (const float*)d_in[18];
    const float* pbnb = (const float*)d_in[19];
    const float* prW1 = (const float*)d_in[20];
    const float* prb1 = (const float*)d_in[21];
    const float* prW2 = (const float*)d_in[22];
    const float* prb2 = (const float*)d_in[23];

    // ---- workspace (~45 MB) ----
    ushort_t* xb  = (ushort_t*)d_ws;              // NN*DD bf16
    ushort_t* yb  = xb + (size_t)NN*DD;
    ushort_t* zb  = yb + (size_t)NN*DD;
    ushort_t* Wf  = zb + (size_t)NN*DD;           // 11*16384 bf16
    float* SR    = (float*)(Wf + 11*16384);       // 8*256 stats regions
    float* yrows = SR + 8*256;                    // 6*128 layer-0 message LUT
    float* hg    = yrows + 6*DD;                  // GG*DD
    float* ph    = hg + (size_t)GG*DD;            // GG*256
    int* cnt    = (int*)(ph + (size_t)GG*256);
    int* inc    = cnt + NN;
    int* rowptr = inc + NN;                       // N+1
    int* cursor = rowptr + NN + 1;
    int* eidx   = cursor + NN;                    // E
    int* goff   = eidx + NE;                      // G+1
    int* bsum   = goff + GG + 1;
    int* boff   = bsum + NB_SCAN;

    float* out_pred   = out;
    float* out_hgraph = out + GG;
    float* out_hmeans = out + GG + GG*DD;

    const int E_GRID   = (NE + 255)/256;          // 2344
    const int AGG_GRID = (NN + 15)/16;            // 3125
    const int GEMM_GRID= (NN + 63)/64;            // 782

    // weight convert -> fragment order
    WPtrs wp;
    for (int i = 0; i < 3; i++){
        wp.p[i]   = linW + (size_t)i*DD*DD;
        wp.p[3+i] = W1   + (size_t)i*DD*DD;
        wp.p[6+i] = W2   + (size_t)i*DD*DD;
    }
    wp.p[9] = pW1; wp.p[10] = pW2;
    k_wconv<<<(11*16384 + 255)/256, 256, 0, stream>>>(wp, Wf);
    const ushort_t* WfLin = Wf;
    const ushort_t* WfW1  = Wf + 3*16384;
    const ushort_t* WfW2  = Wf + 6*16384;
    const ushort_t* WfPW1 = Wf + 9*16384;
    const ushort_t* WfPW2 = Wf + 10*16384;

    // zero stats regions + CSR counters (one pass each)
    hipMemsetAsync(SR, 0, 8*256*sizeof(float), stream);
    hipMemsetAsync(cnt, 0, NN*sizeof(int), stream);

    // graph boundaries + CSR + layer-0 LUT
    k_goff<<<3, 256, 0, stream>>>(bids, goff);
    k_count<<<E_GRID, 256, 0, stream>>>(dst, cnt);
    k_scanA<<<NB_SCAN, 512, 0, stream>>>(cnt, inc, bsum);
    k_scanB<<<1, 64, 0, stream>>>(bsum, boff);
    k_scanC<<<NB_SCAN, 512, 0, stream>>>(cnt, inc, boff, rowptr, cursor);
    k_fill<<<E_GRID, 256, 0, stream>>>(src, dst, cursor, eidx);
    k_lin0<<<6, 128, 0, stream>>>(emb, linW, linB, yrows);

    // ---- layer 0 (6-row LUT path) ----
    k_agg0<<<AGG_GRID, 256, 0, stream>>>(d, emb, yrows, rowptr, eidx, epsA, zb);
    k_gemm<0,0,1><<<GEMM_GRID, 256, 0, stream>>>(zb, WfW1, nullptr, nullptr, nullptr, nullptr, yb, SR + 0*256, NN);
    k_gemm<2,0,1><<<GEMM_GRID, 256, 0, stream>>>(yb, WfW2, nullptr, SR + 0*256, g1, b1, xb, SR + 1*256, NN);
    k_poolbn<<<GG, 128, 0, stream>>>(xb, SR + 1*256, bng, bnb, goff, out_hmeans, nullptr);

    // ---- layers 1,2 ----
    for (int l = 1; l < LL; l++){
        const float* pstat = SR + (2*l - 1)*256;          // outer BN stats of prev layer
        const float* pg    = bng + (size_t)(l-1)*DD;
        const float* pb    = bnb + (size_t)(l-1)*DD;
        float* statsIn  = SR + (2*l)*256;
        float* statsOut = SR + (2*l + 1)*256;

        k_gemm<2,1,0><<<GEMM_GRID, 256, 0, stream>>>(xb, WfLin + (size_t)l*16384, linB + (size_t)l*DD, pstat, pg, pb, yb, nullptr, NN);
        k_agg<<<AGG_GRID, 256, 0, stream>>>(xb, yb, zb, rowptr, eidx, epsA, l, pstat, pg, pb);
        k_gemm<0,0,1><<<GEMM_GRID, 256, 0, stream>>>(zb, WfW1 + (size_t)l*16384, nullptr, nullptr, nullptr, nullptr, yb, statsIn, NN);
        k_gemm<2,0,1><<<GEMM_GRID, 256, 0, stream>>>(yb, WfW2 + (size_t)l*16384, nullptr, statsIn, g1 + (size_t)l*DD, b1 + (size_t)l*DD, xb, statsOut, NN);
        k_poolbn<<<GG, 128, 0, stream>>>(xb, statsOut, bng + (size_t)l*DD, bnb + (size_t)l*DD, goff, out_hmeans + (size_t)l*GG*DD, nullptr);
    }

    // pooling MLP
    k_gemm<2,0,1><<<GEMM_GRID, 256, 0, stream>>>(xb, WfPW1, nullptr, SR + 5*256, bng + 2*DD, bnb + 2*DD, yb, SR + 6*256, NN);
    k_gemm<2,0,1><<<GEMM_GRID, 256, 0, stream>>>(yb, WfPW2, nullptr, SR + 6*256, pg1, pb1, zb, SR + 7*256, NN);
    k_poolbn<<<GG, 128, 0, stream>>>(zb, SR + 7*256, pbng, pbnb, goff, out_hgraph, hg);
    // predict
    k_pred1<<<GG, 256, 0, stream>>>(hg, prW1, prb1, ph);
    k_pred2<<<2, 256, 0, stream>>>(ph, prW2, prb2, out_pred);
}